// Round 3
// baseline (359.634 us; speedup 1.0000x reference)
//
#include <hip/hip_runtime.h>

#define NNODES 50000
#define NCB 196                       // coarse buckets of 256 nodes

typedef __attribute__((ext_vector_type(8))) short bf16x8;
typedef __attribute__((ext_vector_type(4))) float f32x4;

__device__ inline short f2bf(float f) {
    unsigned u = __float_as_uint(f);
    unsigned r = (u + 0x7FFFu + ((u >> 16) & 1u)) >> 16;
    return (short)r;
}
__device__ inline float bf2f(short s) {
    return __uint_as_float(((unsigned)(unsigned short)s) << 16);
}
__device__ inline float2 bfp2f(int p) {   // packed pair: low short = elem 0
    float2 f;
    f.x = __uint_as_float((unsigned)p << 16);
    f.y = __uint_as_float((unsigned)p & 0xFFFF0000u);
    return f;
}
__device__ inline void addbf4(float4& a, int2 v) {
    float2 lo = bfp2f(v.x), hi = bfp2f(v.y);
    a.x += lo.x; a.y += lo.y; a.z += hi.x; a.w += hi.y;
}
// 8 bf16 (int4) -> 8 fp32 accumulate
__device__ inline void addbf8(float* a, int4 v) {
    float2 l0 = bfp2f(v.x), l1 = bfp2f(v.y), l2 = bfp2f(v.z), l3 = bfp2f(v.w);
    a[0] += l0.x; a[1] += l0.y; a[2] += l1.x; a[3] += l1.y;
    a[4] += l2.x; a[5] += l2.y; a[6] += l3.x; a[7] += l3.y;
}
__device__ inline int pack2(float a, float b) {
    return ((int)(unsigned short)f2bf(a)) | ((int)f2bf(b) << 16);
}

// 256-thread exclusive scan (uses lds[0..4]); includes barriers.
__device__ inline int excl_scan_256(int v, int* lds, int tid) {
    int lane = tid & 63, w = tid >> 6;
    int incl = v;
    #pragma unroll
    for (int off = 1; off < 64; off <<= 1) {
        int t = __shfl_up(incl, off, 64);
        if (lane >= off) incl += t;
    }
    if (lane == 63) lds[w] = incl;
    __syncthreads();
    if (tid == 0) {
        int s = 0;
        #pragma unroll
        for (int i = 0; i < 4; i++) { int t = lds[i]; lds[i] = s; s += t; }
    }
    __syncthreads();
    return incl - v + lds[w];
}

// ============== CSR build: contention-free counting sort ====================
__global__ __launch_bounds__(256) void hist_coarse(
    const int* __restrict__ dst, int* __restrict__ histG, int E, int chunk)
{
    __shared__ int h[NCB];
    const int tid = threadIdx.x;
    for (int i = tid; i < NCB; i += 256) h[i] = 0;
    __syncthreads();
    const int beg = blockIdx.x * chunk;
    const int end = min(beg + chunk, E);
    for (int e = beg + tid; e < end; e += 256)
        atomicAdd(&h[dst[e] >> 8], 1);
    __syncthreads();
    for (int i = tid; i < NCB; i += 256)
        histG[i * 256 + blockIdx.x] = h[i];
}

__global__ __launch_bounds__(256) void scan_buckets(
    int* __restrict__ histG, int* __restrict__ btot)
{
    __shared__ int lds[8];
    const int tid = threadIdx.x;
    const int b = blockIdx.x;
    int v = histG[b * 256 + tid];
    int ex = excl_scan_256(v, lds, tid);
    histG[b * 256 + tid] = ex;
    if (tid == 255) btot[b] = ex + v;
}

__global__ __launch_bounds__(256) void scan_bases(
    const int* __restrict__ btot, int* __restrict__ bases, int E)
{
    __shared__ int lds[8];
    const int tid = threadIdx.x;
    int v = (tid < NCB) ? btot[tid] : 0;
    int ex = excl_scan_256(v, lds, tid);
    if (tid <= NCB) bases[tid] = ex;   // bases[NCB] == E
}

__global__ __launch_bounds__(256) void scatter_coarse(
    const int* __restrict__ src, const int* __restrict__ dst,
    const int* __restrict__ histG, const int* __restrict__ bases,
    int* __restrict__ coarse, int E, int chunk)
{
    __shared__ int pos[NCB];
    const int tid = threadIdx.x;
    const int blk = blockIdx.x;
    for (int i = tid; i < NCB; i += 256)
        pos[i] = bases[i] + histG[i * 256 + blk];
    __syncthreads();
    const int beg = blk * chunk;
    const int end = min(beg + chunk, E);
    for (int e = beg + tid; e < end; e += 256) {
        int d = dst[e];
        int p = atomicAdd(&pos[d >> 8], 1);
        coarse[p] = ((d & 255) << 16) | src[e];
    }
}

__global__ __launch_bounds__(256) void fill_from_coarse(
    const int* __restrict__ bases, const int* __restrict__ coarse,
    int* __restrict__ rowptr, int* __restrict__ col, int N)
{
    __shared__ int hist[256], rp[256], pos[256];
    __shared__ int lds[8];
    const int cb  = blockIdx.x;
    const int tid = threadIdx.x;
    const int n0  = cb << 8;
    const int beg = bases[cb], end = bases[cb + 1];
    hist[tid] = 0; pos[tid] = 0;
    __syncthreads();
    for (int e = beg + tid; e < end; e += 256)
        atomicAdd(&hist[coarse[e] >> 16], 1);
    __syncthreads();
    int ex = excl_scan_256(hist[tid], lds, tid);
    rp[tid] = beg + ex;
    if (n0 + tid <= N) rowptr[n0 + tid] = beg + ex;
    __syncthreads();
    for (int e = beg + tid; e < end; e += 256) {
        int pk = coarse[e];
        int dl = pk >> 16;
        int p = atomicAdd(&pos[dl], 1);
        col[rp[dl] + p] = pk & 0xFFFF;
    }
}

// ======================= converts ===========================================
__global__ __launch_bounds__(256) void cvt_x(const float* __restrict__ in,
                                             short* __restrict__ out, int n4) {
    int i = blockIdx.x * 256 + threadIdx.x;
    if (i < n4) {
        float4 v = ((const float4*)in)[i];
        short4 s;
        s.x = f2bf(v.x); s.y = f2bf(v.y); s.z = f2bf(v.z); s.w = f2bf(v.w);
        *(short4*)(out + (size_t)i * 4) = s;
    }
}

__global__ __launch_bounds__(256) void cvt_weights(
    const float* __restrict__ p0, const float* __restrict__ p1,
    const float* __restrict__ p2, const float* __restrict__ p3,
    const float* __restrict__ p4, const float* __restrict__ p5,
    const float* __restrict__ p6, const float* __restrict__ p7,
    short* __restrict__ out) {
    int g = blockIdx.x * 256 + threadIdx.x;
    if (g >= 196608) return;
    const float* src; int off;
    if      (g <  32768) { src = p0; off = g; }
    else if (g <  65536) { src = p1; off = g -  32768; }
    else if (g <  81920) { src = p2; off = g -  65536; }
    else if (g <  98304) { src = p3; off = g -  81920; }
    else if (g < 114688) { src = p4; off = g -  98304; }
    else if (g < 131072) { src = p5; off = g - 114688; }
    else if (g < 163840) { src = p6; off = g - 131072; }
    else                 { src = p7; off = g - 163840; }
    out[g] = f2bf(src[off]);
}

// ====== gather-sum, wide-window (bf16 rows, fp32 accumulate) ================
// D=128 (256B rows): 4 groups x 16 lanes, int4 (16B) per lane,
// 16 edges in flight per window; single masked loop (no serial remainder).
__global__ __launch_bounds__(256) void gather_sum128(
    const short* __restrict__ xbf, const int* __restrict__ rowptr,
    const int* __restrict__ col, short* __restrict__ aggbf, int N)
{
    const int wave = threadIdx.x >> 6;
    const int lane = threadIdx.x & 63;
    const int node = blockIdx.x * 4 + wave;
    if (node >= N) return;
    const int g = lane >> 4;          // edge group 0..3
    const int c = lane & 15;          // int4 slot within row (8 shorts)
    const int beg = rowptr[node], end = rowptr[node + 1];
    float acc[8] = {};
    const int last = end - 1;
    for (int e = beg; e < end; e += 16) {
        const int e0 = e + g, e1 = e + 4 + g, e2 = e + 8 + g, e3 = e + 12 + g;
        const bool m0 = e0 < end, m1 = e1 < end, m2 = e2 < end, m3 = e3 < end;
        const int i0 = col[min(e0, last)];
        const int i1 = col[min(e1, last)];
        const int i2 = col[min(e2, last)];
        const int i3 = col[min(e3, last)];
        int4 v0 = *(const int4*)(xbf + (size_t)i0 * 128 + c * 8);
        int4 v1 = *(const int4*)(xbf + (size_t)i1 * 128 + c * 8);
        int4 v2 = *(const int4*)(xbf + (size_t)i2 * 128 + c * 8);
        int4 v3 = *(const int4*)(xbf + (size_t)i3 * 128 + c * 8);
        if (m0) addbf8(acc, v0);
        if (m1) addbf8(acc, v1);
        if (m2) addbf8(acc, v2);
        if (m3) addbf8(acc, v3);
    }
    #pragma unroll
    for (int k = 0; k < 8; k++) acc[k] += __shfl_down(acc[k], 32);
    #pragma unroll
    for (int k = 0; k < 8; k++) acc[k] += __shfl_down(acc[k], 16);
    if (g == 0) {
        int4 sv;
        sv.x = pack2(acc[0], acc[1]);
        sv.y = pack2(acc[2], acc[3]);
        sv.z = pack2(acc[4], acc[5]);
        sv.w = pack2(acc[6], acc[7]);
        *(int4*)(aggbf + (size_t)node * 128 + c * 8) = sv;
    }
}

// D=64 (128B rows): 8 groups x 8 lanes, int4 per lane, 16 edges/window.
__global__ __launch_bounds__(256) void gather_sum64(
    const short* __restrict__ xbf, const int* __restrict__ rowptr,
    const int* __restrict__ col, short* __restrict__ aggbf, int N)
{
    const int wave = threadIdx.x >> 6;
    const int lane = threadIdx.x & 63;
    const int node = blockIdx.x * 4 + wave;
    if (node >= N) return;
    const int g = lane >> 3;          // edge group 0..7
    const int c = lane & 7;           // int4 slot within row
    const int beg = rowptr[node], end = rowptr[node + 1];
    float acc[8] = {};
    const int last = end - 1;
    for (int e = beg; e < end; e += 16) {
        const int e0 = e + g, e1 = e + 8 + g;
        const bool m0 = e0 < end, m1 = e1 < end;
        const int i0 = col[min(e0, last)];
        const int i1 = col[min(e1, last)];
        int4 v0 = *(const int4*)(xbf + (size_t)i0 * 64 + c * 8);
        int4 v1 = *(const int4*)(xbf + (size_t)i1 * 64 + c * 8);
        if (m0) addbf8(acc, v0);
        if (m1) addbf8(acc, v1);
    }
    #pragma unroll
    for (int k = 0; k < 8; k++) acc[k] += __shfl_down(acc[k], 32);
    #pragma unroll
    for (int k = 0; k < 8; k++) acc[k] += __shfl_down(acc[k], 16);
    #pragma unroll
    for (int k = 0; k < 8; k++) acc[k] += __shfl_down(acc[k], 8);
    if (g == 0) {
        int4 sv;
        sv.x = pack2(acc[0], acc[1]);
        sv.y = pack2(acc[2], acc[3]);
        sv.z = pack2(acc[4], acc[5]);
        sv.w = pack2(acc[6], acc[7]);
        *(int4*)(aggbf + (size_t)node * 64 + c * 8) = sv;
    }
}

// ==== gather_fin128: out128 = lrelu(seg_sum(z[src]) + w + b), zw N x 256 ====
__global__ __launch_bounds__(256) void gather_fin128(
    const short* __restrict__ zw, const int* __restrict__ rowptr,
    const int* __restrict__ col, const float* __restrict__ bias,
    float* __restrict__ out, int N)
{
    const int wave = threadIdx.x >> 6;
    const int lane = threadIdx.x & 63;
    const int node = blockIdx.x * 4 + wave;
    if (node >= N) return;
    const int g = lane >> 4;
    const int c = lane & 15;
    const int beg = rowptr[node], end = rowptr[node + 1];
    float acc[8] = {};
    if (g == 0) {   // root part + bias, added once
        int4 wv = *(const int4*)(zw + (size_t)node * 256 + 128 + c * 8);
        addbf8(acc, wv);
        float4 b0 = *(const float4*)(bias + c * 8);
        float4 b1 = *(const float4*)(bias + c * 8 + 4);
        acc[0] += b0.x; acc[1] += b0.y; acc[2] += b0.z; acc[3] += b0.w;
        acc[4] += b1.x; acc[5] += b1.y; acc[6] += b1.z; acc[7] += b1.w;
    }
    const int last = end - 1;
    for (int e = beg; e < end; e += 16) {
        const int e0 = e + g, e1 = e + 4 + g, e2 = e + 8 + g, e3 = e + 12 + g;
        const bool m0 = e0 < end, m1 = e1 < end, m2 = e2 < end, m3 = e3 < end;
        const int i0 = col[min(e0, last)];
        const int i1 = col[min(e1, last)];
        const int i2 = col[min(e2, last)];
        const int i3 = col[min(e3, last)];
        int4 v0 = *(const int4*)(zw + (size_t)i0 * 256 + c * 8);
        int4 v1 = *(const int4*)(zw + (size_t)i1 * 256 + c * 8);
        int4 v2 = *(const int4*)(zw + (size_t)i2 * 256 + c * 8);
        int4 v3 = *(const int4*)(zw + (size_t)i3 * 256 + c * 8);
        if (m0) addbf8(acc, v0);
        if (m1) addbf8(acc, v1);
        if (m2) addbf8(acc, v2);
        if (m3) addbf8(acc, v3);
    }
    #pragma unroll
    for (int k = 0; k < 8; k++) acc[k] += __shfl_down(acc[k], 32);
    #pragma unroll
    for (int k = 0; k < 8; k++) acc[k] += __shfl_down(acc[k], 16);
    if (g == 0) {
        #pragma unroll
        for (int k = 0; k < 8; k++) acc[k] = acc[k] > 0.f ? acc[k] : 0.01f * acc[k];
        float4 o0 = make_float4(acc[0], acc[1], acc[2], acc[3]);
        float4 o1 = make_float4(acc[4], acc[5], acc[6], acc[7]);
        *(float4*)(out + (size_t)node * 128 + c * 8)     = o0;
        *(float4*)(out + (size_t)node * 128 + c * 8 + 4) = o1;
    }
}

// ==== gather_fin64: emb = lrelu(seg_sum(z[src]) + w + b), zw N x 128 ========
__global__ __launch_bounds__(256) void gather_fin64(
    const short* __restrict__ zw, const int* __restrict__ rowptr,
    const int* __restrict__ col, const float* __restrict__ bias,
    float* __restrict__ out, short* __restrict__ out_bf, int N)
{
    const int wave = threadIdx.x >> 6;
    const int lane = threadIdx.x & 63;
    const int node = blockIdx.x * 4 + wave;
    if (node >= N) return;
    const int g = lane >> 3;
    const int c = lane & 7;
    const int beg = rowptr[node], end = rowptr[node + 1];
    float acc[8] = {};
    if (g == 0) {
        int4 wv = *(const int4*)(zw + (size_t)node * 128 + 64 + c * 8);
        addbf8(acc, wv);
        float4 b0 = *(const float4*)(bias + c * 8);
        float4 b1 = *(const float4*)(bias + c * 8 + 4);
        acc[0] += b0.x; acc[1] += b0.y; acc[2] += b0.z; acc[3] += b0.w;
        acc[4] += b1.x; acc[5] += b1.y; acc[6] += b1.z; acc[7] += b1.w;
    }
    const int last = end - 1;
    for (int e = beg; e < end; e += 16) {
        const int e0 = e + g, e1 = e + 8 + g;
        const bool m0 = e0 < end, m1 = e1 < end;
        const int i0 = col[min(e0, last)];
        const int i1 = col[min(e1, last)];
        int4 v0 = *(const int4*)(zw + (size_t)i0 * 128 + c * 8);
        int4 v1 = *(const int4*)(zw + (size_t)i1 * 128 + c * 8);
        if (m0) addbf8(acc, v0);
        if (m1) addbf8(acc, v1);
    }
    #pragma unroll
    for (int k = 0; k < 8; k++) acc[k] += __shfl_down(acc[k], 32);
    #pragma unroll
    for (int k = 0; k < 8; k++) acc[k] += __shfl_down(acc[k], 16);
    #pragma unroll
    for (int k = 0; k < 8; k++) acc[k] += __shfl_down(acc[k], 8);
    if (g == 0) {
        #pragma unroll
        for (int k = 0; k < 8; k++) acc[k] = acc[k] > 0.f ? acc[k] : 0.01f * acc[k];
        float4 o0 = make_float4(acc[0], acc[1], acc[2], acc[3]);
        float4 o1 = make_float4(acc[4], acc[5], acc[6], acc[7]);
        *(float4*)(out + (size_t)node * 64 + c * 8)     = o0;
        *(float4*)(out + (size_t)node * 64 + c * 8 + 4) = o1;
        int4 sv;
        sv.x = pack2(acc[0], acc[1]);
        sv.y = pack2(acc[2], acc[3]);
        sv.z = pack2(acc[4], acc[5]);
        sv.w = pack2(acc[6], acc[7]);
        *(int4*)(out_bf + (size_t)node * 64 + c * 8) = sv;
    }
}

// ======================= MFMA GEMM (LDS-free main loop) =====================
// A and B fragments read directly from global (B is <=128KB -> L2-resident).
// Operand-swapped MFMA (lane holds row m16, cols quad*4+r). Wave-private LDS
// scratch transposes C fragments for 16B coalesced stores. No barriers.
template<int DK, int DOUT, bool FUSED>
__global__ __launch_bounds__(256, 4) void gemm_mfma(
    const short* __restrict__ A0, const short* __restrict__ A1,
    const short* __restrict__ B0, const short* __restrict__ B1,
    const float* __restrict__ bias, short* __restrict__ outH, int N)
{
    constexpr int KTOT  = FUSED ? 2 * DK : DK;
    constexpr int NCOLS = FUSED ? DOUT : 2 * DOUT;
    constexpr int K32   = KTOT / 32;

    __shared__ short eps[4 * 4608];              // 9KB per wave, private
    const int tid  = threadIdx.x;
    const int row0 = blockIdx.x * 128;
    const int col0 = blockIdx.y * 128;
    const int w    = tid >> 6;
    const int lane = tid & 63;
    const int wr   = (w & 1) << 6;               // row half 0/64
    const int wc   = (w >> 1) << 6;              // col slab 0/64
    const int m16  = lane & 15;
    const int quad = lane >> 4;

    // A row pointers (lane's output row), pre-offset by quad*8 shorts
    const short* arow[4];
    #pragma unroll
    for (int i = 0; i < 4; i++) {
        int r = row0 + wr + i * 16 + m16;
        r = r < N ? r : N - 1;
        arow[i] = A0 + (size_t)r * DK + (quad << 3);
    }
    const size_t a1d = FUSED ? (size_t)(A1 - A0) : 0;

    // B row pointers (lane's output cols live in B row cg)
    const short* blo[4];
    const short* bhi[4];
    #pragma unroll
    for (int j = 0; j < 4; j++) {
        const int cg = col0 + wc + j * 16 + m16;
        if (FUSED) {
            blo[j] = B0 + (size_t)cg * DK + (quad << 3);
            bhi[j] = B1 + (size_t)cg * DK + (quad << 3);
        } else {
            blo[j] = ((cg < DOUT) ? (B0 + (size_t)cg * DK)
                                  : (B1 + (size_t)(cg - DOUT) * DK)) + (quad << 3);
            bhi[j] = blo[j];
        }
    }

    f32x4 acc[4][4] = {};

    #pragma unroll
    for (int kk = 0; kk < K32; kk++) {
        const int ko = kk * 32;
        bf16x8 af[4];
        #pragma unroll
        for (int i = 0; i < 4; i++) {
            const short* ap = arow[i];
            if (FUSED && ko >= DK) ap += a1d + (ko - DK);
            else                   ap += ko;
            af[i] = *(const bf16x8*)ap;
        }
        #pragma unroll
        for (int j = 0; j < 4; j++) {
            const short* bp;
            if (FUSED && ko >= DK) bp = bhi[j] + (ko - DK);
            else                   bp = blo[j] + ko;
            bf16x8 bfr = *(const bf16x8*)bp;
            // swapped operands: lane's output row = m16, cols = quad*4+r
            #pragma unroll
            for (int i = 0; i < 4; i++)
                acc[i][j] = __builtin_amdgcn_mfma_f32_16x16x32_bf16(
                    bfr, af[i], acc[i][j], 0, 0, 0);
        }
    }

    // ---- wave-private transpose epilogue: int2 LDS writes, int4 reads ----
    short* ep = eps + w * 4608;
    #pragma unroll
    for (int j = 0; j < 4; j++) {
        const int cb = wc + j * 16 + (quad << 2);
        float4 bv = make_float4(0.f, 0.f, 0.f, 0.f);
        if (FUSED) bv = *(const float4*)(bias + col0 + cb);
        #pragma unroll
        for (int i = 0; i < 4; i++) {
            float v0 = acc[i][j][0], v1 = acc[i][j][1];
            float v2 = acc[i][j][2], v3 = acc[i][j][3];
            if (FUSED) {
                v0 += bv.x; v1 += bv.y; v2 += bv.z; v3 += bv.w;
                v0 = v0 > 0.f ? v0 : 0.01f * v0;
                v1 = v1 > 0.f ? v1 : 0.01f * v1;
                v2 = v2 > 0.f ? v2 : 0.01f * v2;
                v3 = v3 > 0.f ? v3 : 0.01f * v3;
            }
            int2 pv;
            pv.x = pack2(v0, v1);
            pv.y = pack2(v2, v3);
            *(int2*)(ep + (i * 16 + m16) * 72 + j * 16 + (quad << 2)) = pv;
        }
    }
    const int r8  = lane >> 3;
    const int seg = lane & 7;
    #pragma unroll
    for (int rb = 0; rb < 8; rb++) {
        const int lrow = rb * 8 + r8;
        int4 vv = *(const int4*)(ep + lrow * 72 + seg * 8);
        const int grow = row0 + wr + lrow;
        if (grow < N)
            *(int4*)(outH + (size_t)grow * NCOLS + col0 + wc + seg * 8) = vv;
    }
}

extern "C" void kernel_launch(void* const* d_in, const int* in_sizes, int n_in,
                              void* d_out, int out_size, void* d_ws, size_t ws_size,
                              hipStream_t stream) {
    const int N = NNODES;
    const float* x  = (const float*)d_in[0];
    const int*   ei = (const int*)d_in[1];
    const int    E  = in_sizes[1] / 2;
    const int* src = ei;
    const int* dst = ei + E;

    const float* Wr[4] = { (const float*)d_in[2], (const float*)d_in[5],
                           (const float*)d_in[8], (const float*)d_in[11] };
    const float* Ws[4] = { (const float*)d_in[3], (const float*)d_in[6],
                           (const float*)d_in[9], (const float*)d_in[12] };
    const float* bb[4] = { (const float*)d_in[4], (const float*)d_in[7],
                           (const float*)d_in[10], (const float*)d_in[13] };

    float* out  = (float*)d_out;                     // h_final: N x 128 fp32
    float* emb  = out + (size_t)N * 128;             // emb:     N x 64 fp32

    // workspace layout
    short* zwbf   = (short*)d_ws;                    // N x 256 bf16 (z|w)
    short* aggbf  = zwbf + (size_t)N * 256;          // N x 128 bf16
    short* xbf    = aggbf + (size_t)N * 128;         // N x 128 bf16
    short* h1bf   = xbf + (size_t)N * 128;           // N x 256 bf16 (also h3)
    short* embbf  = h1bf + (size_t)N * 256;          // N x 64 bf16
    short* wbf    = embbf + (size_t)N * 64;          // 196608 bf16 weights
    int*   rowptr = (int*)(wbf + 196608);            // N+1
    int*   col    = rowptr + (N + 1);                // E
    int*   coarse = col + E;                         // E
    int*   histG  = coarse + E;                      // NCB*256
    int*   btot   = histG + NCB * 256;               // NCB
    int*   bases  = btot + NCB;                      // NCB+1

    const short* wr0 = wbf;           const short* ws0 = wbf + 32768;
    const short* wr1 = wbf + 65536;   const short* ws1 = wbf + 81920;
    const short* wr2 = wbf + 98304;   const short* ws2 = wbf + 114688;
    const short* wr3 = wbf + 131072;  const short* ws3 = wbf + 163840;

    const int chunk = (E + 255) / 256;
    const int gemmRB = (N + 127) / 128;              // 391
    const int nodeBlocks = (N + 3) / 4;

    // ---- CSR build (contention-free counting sort) + converts ----
    hist_coarse<<<256, 256, 0, stream>>>(dst, histG, E, chunk);
    scan_buckets<<<NCB, 256, 0, stream>>>(histG, btot);
    scan_bases<<<1, 256, 0, stream>>>(btot, bases, E);
    scatter_coarse<<<256, 256, 0, stream>>>(src, dst, histG, bases, coarse, E, chunk);
    fill_from_coarse<<<NCB, 256, 0, stream>>>(bases, coarse, rowptr, col, N);
    cvt_x<<<(N * 128 / 4 + 255) / 256, 256, 0, stream>>>(x, xbf, N * 128 / 4);
    cvt_weights<<<(196608 + 255) / 256, 256, 0, stream>>>(
        Wr[0], Ws[0], Wr[1], Ws[1], Wr[2], Ws[2], Wr[3], Ws[3], wbf);

    // ---- Layer 0 (gather-first): 128 -> 256 ----
    gather_sum128<<<nodeBlocks, 256, 0, stream>>>(xbf, rowptr, col, aggbf, N);
    gemm_mfma<128, 256, true><<<dim3(gemmRB, 2), 256, 0, stream>>>(
        aggbf, xbf, wr0, ws0, bb[0], h1bf, N);

    // ---- Layer 1 (GEMM-first): 256 -> 64 ----
    gemm_mfma<256, 64, false><<<dim3(gemmRB, 1), 256, 0, stream>>>(
        h1bf, nullptr, wr1, ws1, nullptr, zwbf, N);            // zw1: N x 128
    gather_fin64<<<nodeBlocks, 256, 0, stream>>>(
        zwbf, rowptr, col, bb[1], emb, embbf, N);

    // ---- Layer 2 (gather-first): 64 -> 256 ----
    gather_sum64<<<nodeBlocks, 256, 0, stream>>>(embbf, rowptr, col, aggbf, N);
    gemm_mfma<64, 256, true><<<dim3(gemmRB, 2), 256, 0, stream>>>(
        aggbf, embbf, wr2, ws2, bb[2], h1bf /*h3bf*/, N);

    // ---- Layer 3 (GEMM-first): 256 -> 128 ----
    gemm_mfma<256, 128, false><<<dim3(gemmRB, 2), 256, 0, stream>>>(
        h1bf /*h3bf*/, nullptr, wr3, ws3, nullptr, zwbf, N);   // zw3: N x 256
    gather_fin128<<<nodeBlocks, 256, 0, stream>>>(
        zwbf, rowptr, col, bb[3], out, N);
}

// Round 4
// 324.026 us; speedup vs baseline: 1.1099x; 1.1099x over previous
//
#include <hip/hip_runtime.h>

#define NNODES 50000
#define NCB 196                       // coarse buckets of 256 nodes

typedef __attribute__((ext_vector_type(8))) short bf16x8;
typedef __attribute__((ext_vector_type(4))) float f32x4;

#define AS1 __attribute__((address_space(1)))
#define AS3 __attribute__((address_space(3)))

__device__ inline short f2bf(float f) {
    unsigned u = __float_as_uint(f);
    unsigned r = (u + 0x7FFFu + ((u >> 16) & 1u)) >> 16;
    return (short)r;
}
__device__ inline float bf2f(short s) {
    return __uint_as_float(((unsigned)(unsigned short)s) << 16);
}
__device__ inline float2 bfp2f(int p) {   // packed pair: low short = elem 0
    float2 f;
    f.x = __uint_as_float((unsigned)p << 16);
    f.y = __uint_as_float((unsigned)p & 0xFFFF0000u);
    return f;
}
__device__ inline void addbf4(float4& a, int2 v) {
    float2 lo = bfp2f(v.x), hi = bfp2f(v.y);
    a.x += lo.x; a.y += lo.y; a.z += hi.x; a.w += hi.y;
}
// 8 bf16 (int4) -> 8 fp32 accumulate
__device__ inline void addbf8(float* a, int4 v) {
    float2 l0 = bfp2f(v.x), l1 = bfp2f(v.y), l2 = bfp2f(v.z), l3 = bfp2f(v.w);
    a[0] += l0.x; a[1] += l0.y; a[2] += l1.x; a[3] += l1.y;
    a[4] += l2.x; a[5] += l2.y; a[6] += l3.x; a[7] += l3.y;
}
__device__ inline int pack2(float a, float b) {
    return ((int)(unsigned short)f2bf(a)) | ((int)f2bf(b) << 16);
}

// 256-thread exclusive scan (uses lds[0..4]); includes barriers.
__device__ inline int excl_scan_256(int v, int* lds, int tid) {
    int lane = tid & 63, w = tid >> 6;
    int incl = v;
    #pragma unroll
    for (int off = 1; off < 64; off <<= 1) {
        int t = __shfl_up(incl, off, 64);
        if (lane >= off) incl += t;
    }
    if (lane == 63) lds[w] = incl;
    __syncthreads();
    if (tid == 0) {
        int s = 0;
        #pragma unroll
        for (int i = 0; i < 4; i++) { int t = lds[i]; lds[i] = s; s += t; }
    }
    __syncthreads();
    return incl - v + lds[w];
}

// ============== CSR build: contention-free counting sort ====================
__global__ __launch_bounds__(256) void hist_coarse(
    const int* __restrict__ dst, int* __restrict__ histG, int E, int chunk)
{
    __shared__ int h[NCB];
    const int tid = threadIdx.x;
    for (int i = tid; i < NCB; i += 256) h[i] = 0;
    __syncthreads();
    const int beg = blockIdx.x * chunk;
    const int end = min(beg + chunk, E);
    for (int e = beg + tid; e < end; e += 256)
        atomicAdd(&h[dst[e] >> 8], 1);
    __syncthreads();
    for (int i = tid; i < NCB; i += 256)
        histG[i * 256 + blockIdx.x] = h[i];
}

__global__ __launch_bounds__(256) void scan_buckets(
    int* __restrict__ histG, int* __restrict__ btot)
{
    __shared__ int lds[8];
    const int tid = threadIdx.x;
    const int b = blockIdx.x;
    int v = histG[b * 256 + tid];
    int ex = excl_scan_256(v, lds, tid);
    histG[b * 256 + tid] = ex;
    if (tid == 255) btot[b] = ex + v;
}

__global__ __launch_bounds__(256) void scan_bases(
    const int* __restrict__ btot, int* __restrict__ bases, int E)
{
    __shared__ int lds[8];
    const int tid = threadIdx.x;
    int v = (tid < NCB) ? btot[tid] : 0;
    int ex = excl_scan_256(v, lds, tid);
    if (tid <= NCB) bases[tid] = ex;   // bases[NCB] == E
}

__global__ __launch_bounds__(256) void scatter_coarse(
    const int* __restrict__ src, const int* __restrict__ dst,
    const int* __restrict__ histG, const int* __restrict__ bases,
    int* __restrict__ coarse, int E, int chunk)
{
    __shared__ int pos[NCB];
    const int tid = threadIdx.x;
    const int blk = blockIdx.x;
    for (int i = tid; i < NCB; i += 256)
        pos[i] = bases[i] + histG[i * 256 + blk];
    __syncthreads();
    const int beg = blk * chunk;
    const int end = min(beg + chunk, E);
    for (int e = beg + tid; e < end; e += 256) {
        int d = dst[e];
        int p = atomicAdd(&pos[d >> 8], 1);
        coarse[p] = ((d & 255) << 16) | src[e];
    }
}

__global__ __launch_bounds__(256) void fill_from_coarse(
    const int* __restrict__ bases, const int* __restrict__ coarse,
    int* __restrict__ rowptr, int* __restrict__ col, int N)
{
    __shared__ int hist[256], rp[256], pos[256];
    __shared__ int lds[8];
    const int cb  = blockIdx.x;
    const int tid = threadIdx.x;
    const int n0  = cb << 8;
    const int beg = bases[cb], end = bases[cb + 1];
    hist[tid] = 0; pos[tid] = 0;
    __syncthreads();
    for (int e = beg + tid; e < end; e += 256)
        atomicAdd(&hist[coarse[e] >> 16], 1);
    __syncthreads();
    int ex = excl_scan_256(hist[tid], lds, tid);
    rp[tid] = beg + ex;
    if (n0 + tid <= N) rowptr[n0 + tid] = beg + ex;
    __syncthreads();
    for (int e = beg + tid; e < end; e += 256) {
        int pk = coarse[e];
        int dl = pk >> 16;
        int p = atomicAdd(&pos[dl], 1);
        col[rp[dl] + p] = pk & 0xFFFF;
    }
}

// ======================= converts ===========================================
__global__ __launch_bounds__(256) void cvt_x(const float* __restrict__ in,
                                             short* __restrict__ out, int n4) {
    int i = blockIdx.x * 256 + threadIdx.x;
    if (i < n4) {
        float4 v = ((const float4*)in)[i];
        short4 s;
        s.x = f2bf(v.x); s.y = f2bf(v.y); s.z = f2bf(v.z); s.w = f2bf(v.w);
        *(short4*)(out + (size_t)i * 4) = s;
    }
}

__global__ __launch_bounds__(256) void cvt_weights(
    const float* __restrict__ p0, const float* __restrict__ p1,
    const float* __restrict__ p2, const float* __restrict__ p3,
    const float* __restrict__ p4, const float* __restrict__ p5,
    const float* __restrict__ p6, const float* __restrict__ p7,
    short* __restrict__ out) {
    int g = blockIdx.x * 256 + threadIdx.x;
    if (g >= 196608) return;
    const float* src; int off;
    if      (g <  32768) { src = p0; off = g; }
    else if (g <  65536) { src = p1; off = g -  32768; }
    else if (g <  81920) { src = p2; off = g -  65536; }
    else if (g <  98304) { src = p3; off = g -  81920; }
    else if (g < 114688) { src = p4; off = g -  98304; }
    else if (g < 131072) { src = p5; off = g - 114688; }
    else if (g < 163840) { src = p6; off = g - 131072; }
    else                 { src = p7; off = g - 163840; }
    out[g] = f2bf(src[off]);
}

// ====== gather-sum, wide-window (bf16 rows, fp32 accumulate) ================
__global__ __launch_bounds__(256) void gather_sum128(
    const short* __restrict__ xbf, const int* __restrict__ rowptr,
    const int* __restrict__ col, short* __restrict__ aggbf, int N)
{
    const int wave = threadIdx.x >> 6;
    const int lane = threadIdx.x & 63;
    const int node = blockIdx.x * 4 + wave;
    if (node >= N) return;
    const int g = lane >> 4;          // edge group 0..3
    const int c = lane & 15;          // int4 slot within row (8 shorts)
    const int beg = rowptr[node], end = rowptr[node + 1];
    float acc[8] = {};
    const int last = end - 1;
    for (int e = beg; e < end; e += 16) {
        const int e0 = e + g, e1 = e + 4 + g, e2 = e + 8 + g, e3 = e + 12 + g;
        const bool m0 = e0 < end, m1 = e1 < end, m2 = e2 < end, m3 = e3 < end;
        const int i0 = col[min(e0, last)];
        const int i1 = col[min(e1, last)];
        const int i2 = col[min(e2, last)];
        const int i3 = col[min(e3, last)];
        int4 v0 = *(const int4*)(xbf + (size_t)i0 * 128 + c * 8);
        int4 v1 = *(const int4*)(xbf + (size_t)i1 * 128 + c * 8);
        int4 v2 = *(const int4*)(xbf + (size_t)i2 * 128 + c * 8);
        int4 v3 = *(const int4*)(xbf + (size_t)i3 * 128 + c * 8);
        if (m0) addbf8(acc, v0);
        if (m1) addbf8(acc, v1);
        if (m2) addbf8(acc, v2);
        if (m3) addbf8(acc, v3);
    }
    #pragma unroll
    for (int k = 0; k < 8; k++) acc[k] += __shfl_down(acc[k], 32);
    #pragma unroll
    for (int k = 0; k < 8; k++) acc[k] += __shfl_down(acc[k], 16);
    if (g == 0) {
        int4 sv;
        sv.x = pack2(acc[0], acc[1]);
        sv.y = pack2(acc[2], acc[3]);
        sv.z = pack2(acc[4], acc[5]);
        sv.w = pack2(acc[6], acc[7]);
        *(int4*)(aggbf + (size_t)node * 128 + c * 8) = sv;
    }
}

__global__ __launch_bounds__(256) void gather_sum64(
    const short* __restrict__ xbf, const int* __restrict__ rowptr,
    const int* __restrict__ col, short* __restrict__ aggbf, int N)
{
    const int wave = threadIdx.x >> 6;
    const int lane = threadIdx.x & 63;
    const int node = blockIdx.x * 4 + wave;
    if (node >= N) return;
    const int g = lane >> 3;          // edge group 0..7
    const int c = lane & 7;           // int4 slot within row
    const int beg = rowptr[node], end = rowptr[node + 1];
    float acc[8] = {};
    const int last = end - 1;
    for (int e = beg; e < end; e += 16) {
        const int e0 = e + g, e1 = e + 8 + g;
        const bool m0 = e0 < end, m1 = e1 < end;
        const int i0 = col[min(e0, last)];
        const int i1 = col[min(e1, last)];
        int4 v0 = *(const int4*)(xbf + (size_t)i0 * 64 + c * 8);
        int4 v1 = *(const int4*)(xbf + (size_t)i1 * 64 + c * 8);
        if (m0) addbf8(acc, v0);
        if (m1) addbf8(acc, v1);
    }
    #pragma unroll
    for (int k = 0; k < 8; k++) acc[k] += __shfl_down(acc[k], 32);
    #pragma unroll
    for (int k = 0; k < 8; k++) acc[k] += __shfl_down(acc[k], 16);
    #pragma unroll
    for (int k = 0; k < 8; k++) acc[k] += __shfl_down(acc[k], 8);
    if (g == 0) {
        int4 sv;
        sv.x = pack2(acc[0], acc[1]);
        sv.y = pack2(acc[2], acc[3]);
        sv.z = pack2(acc[4], acc[5]);
        sv.w = pack2(acc[6], acc[7]);
        *(int4*)(aggbf + (size_t)node * 64 + c * 8) = sv;
    }
}

// ==== gather_fin128: out128 = lrelu(seg_sum(z[src]) + w + b), zw N x 256 ====
__global__ __launch_bounds__(256) void gather_fin128(
    const short* __restrict__ zw, const int* __restrict__ rowptr,
    const int* __restrict__ col, const float* __restrict__ bias,
    float* __restrict__ out, int N)
{
    const int wave = threadIdx.x >> 6;
    const int lane = threadIdx.x & 63;
    const int node = blockIdx.x * 4 + wave;
    if (node >= N) return;
    const int g = lane >> 4;
    const int c = lane & 15;
    const int beg = rowptr[node], end = rowptr[node + 1];
    float acc[8] = {};
    if (g == 0) {   // root part + bias, added once
        int4 wv = *(const int4*)(zw + (size_t)node * 256 + 128 + c * 8);
        addbf8(acc, wv);
        float4 b0 = *(const float4*)(bias + c * 8);
        float4 b1 = *(const float4*)(bias + c * 8 + 4);
        acc[0] += b0.x; acc[1] += b0.y; acc[2] += b0.z; acc[3] += b0.w;
        acc[4] += b1.x; acc[5] += b1.y; acc[6] += b1.z; acc[7] += b1.w;
    }
    const int last = end - 1;
    for (int e = beg; e < end; e += 16) {
        const int e0 = e + g, e1 = e + 4 + g, e2 = e + 8 + g, e3 = e + 12 + g;
        const bool m0 = e0 < end, m1 = e1 < end, m2 = e2 < end, m3 = e3 < end;
        const int i0 = col[min(e0, last)];
        const int i1 = col[min(e1, last)];
        const int i2 = col[min(e2, last)];
        const int i3 = col[min(e3, last)];
        int4 v0 = *(const int4*)(zw + (size_t)i0 * 256 + c * 8);
        int4 v1 = *(const int4*)(zw + (size_t)i1 * 256 + c * 8);
        int4 v2 = *(const int4*)(zw + (size_t)i2 * 256 + c * 8);
        int4 v3 = *(const int4*)(zw + (size_t)i3 * 256 + c * 8);
        if (m0) addbf8(acc, v0);
        if (m1) addbf8(acc, v1);
        if (m2) addbf8(acc, v2);
        if (m3) addbf8(acc, v3);
    }
    #pragma unroll
    for (int k = 0; k < 8; k++) acc[k] += __shfl_down(acc[k], 32);
    #pragma unroll
    for (int k = 0; k < 8; k++) acc[k] += __shfl_down(acc[k], 16);
    if (g == 0) {
        #pragma unroll
        for (int k = 0; k < 8; k++) acc[k] = acc[k] > 0.f ? acc[k] : 0.01f * acc[k];
        float4 o0 = make_float4(acc[0], acc[1], acc[2], acc[3]);
        float4 o1 = make_float4(acc[4], acc[5], acc[6], acc[7]);
        *(float4*)(out + (size_t)node * 128 + c * 8)     = o0;
        *(float4*)(out + (size_t)node * 128 + c * 8 + 4) = o1;
    }
}

// ==== gather_fin64: emb = lrelu(seg_sum(z[src]) + w + b), zw N x 128 ========
__global__ __launch_bounds__(256) void gather_fin64(
    const short* __restrict__ zw, const int* __restrict__ rowptr,
    const int* __restrict__ col, const float* __restrict__ bias,
    float* __restrict__ out, short* __restrict__ out_bf, int N)
{
    const int wave = threadIdx.x >> 6;
    const int lane = threadIdx.x & 63;
    const int node = blockIdx.x * 4 + wave;
    if (node >= N) return;
    const int g = lane >> 3;
    const int c = lane & 7;
    const int beg = rowptr[node], end = rowptr[node + 1];
    float acc[8] = {};
    if (g == 0) {
        int4 wv = *(const int4*)(zw + (size_t)node * 128 + 64 + c * 8);
        addbf8(acc, wv);
        float4 b0 = *(const float4*)(bias + c * 8);
        float4 b1 = *(const float4*)(bias + c * 8 + 4);
        acc[0] += b0.x; acc[1] += b0.y; acc[2] += b0.z; acc[3] += b0.w;
        acc[4] += b1.x; acc[5] += b1.y; acc[6] += b1.z; acc[7] += b1.w;
    }
    const int last = end - 1;
    for (int e = beg; e < end; e += 16) {
        const int e0 = e + g, e1 = e + 8 + g;
        const bool m0 = e0 < end, m1 = e1 < end;
        const int i0 = col[min(e0, last)];
        const int i1 = col[min(e1, last)];
        int4 v0 = *(const int4*)(zw + (size_t)i0 * 128 + c * 8);
        int4 v1 = *(const int4*)(zw + (size_t)i1 * 128 + c * 8);
        if (m0) addbf8(acc, v0);
        if (m1) addbf8(acc, v1);
    }
    #pragma unroll
    for (int k = 0; k < 8; k++) acc[k] += __shfl_down(acc[k], 32);
    #pragma unroll
    for (int k = 0; k < 8; k++) acc[k] += __shfl_down(acc[k], 16);
    #pragma unroll
    for (int k = 0; k < 8; k++) acc[k] += __shfl_down(acc[k], 8);
    if (g == 0) {
        #pragma unroll
        for (int k = 0; k < 8; k++) acc[k] = acc[k] > 0.f ? acc[k] : 0.01f * acc[k];
        float4 o0 = make_float4(acc[0], acc[1], acc[2], acc[3]);
        float4 o1 = make_float4(acc[4], acc[5], acc[6], acc[7]);
        *(float4*)(out + (size_t)node * 64 + c * 8)     = o0;
        *(float4*)(out + (size_t)node * 64 + c * 8 + 4) = o1;
        int4 sv;
        sv.x = pack2(acc[0], acc[1]);
        sv.y = pack2(acc[2], acc[3]);
        sv.z = pack2(acc[4], acc[5]);
        sv.w = pack2(acc[6], acc[7]);
        *(int4*)(out_bf + (size_t)node * 64 + c * 8) = sv;
    }
}

// ======================= MFMA GEMM ==========================================
// 256-row x 128-col tile, 512 threads (8 waves: 4 row-halves x 2 col slabs).
// B tile (<=64KB) staged once via global_load_lds (linear dest, permuted
// source). K-loop: A from global, B via ds_read_b128, swapped-operand MFMA.
// Wave-private transpose epilogue (int2 LDS writes, int4 coalesced stores).
template<int DK, int DOUT, bool FUSED>
__global__ __launch_bounds__(512, 2) void gemm_mfma(
    const short* __restrict__ A0, const short* __restrict__ A1,
    const short* __restrict__ B0, const short* __restrict__ B1,
    const float* __restrict__ bias, short* __restrict__ outH, int N)
{
    constexpr int KTOT  = FUSED ? 2 * DK : DK;
    constexpr int NCOLS = FUSED ? DOUT : 2 * DOUT;
    constexpr int K32   = KTOT / 32;
    constexpr int LOG2K32 = (K32 == 8) ? 3 : 2;
    constexpr int BSH   = 128 * KTOT;            // B tile, shorts
    constexpr int BI4   = BSH / 8;               // int4 units
    constexpr int ITER  = BI4 / 512;
    constexpr int EPSH  = 8 * 4608;              // epilogue scratch, shorts
    constexpr int SMSH  = (BSH > EPSH) ? BSH : EPSH;

    __shared__ short smem[SMSH];
    const int tid  = threadIdx.x;
    const int row0 = blockIdx.x * 256;
    const int col0 = blockIdx.y * 128;
    const int w    = tid >> 6;
    const int lane = tid & 63;
    const int wr   = (w & 3) << 6;               // row quarter 0/64/128/192
    const int wc   = (w >> 2) << 6;              // col slab 0/64
    const int m16  = lane & 15;
    const int quad = lane >> 4;

    // ---- stage B tile via async global->LDS: linear LDS int4-index L
    //      corresponds to [jj][kk][qd][mm]; source address permuted. ----
    #pragma unroll
    for (int it = 0; it < ITER; it++) {
        const int L  = tid + it * 512;
        const int mm = L & 15;
        const int qd = (L >> 4) & 3;
        const int kk = (L >> 6) & (K32 - 1);
        const int jj = L >> (6 + LOG2K32);
        const int j  = col0 + jj * 16 + mm;
        const int ko = (kk * 4 + qd) * 8;
        const short* bp;
        if (FUSED) {
            if (ko < DK) bp = B0 + (size_t)j * DK + ko;
            else         bp = B1 + (size_t)j * DK + (ko - DK);
        } else {
            bp = (j < DOUT) ? (B0 + (size_t)j * DK + ko)
                            : (B1 + (size_t)(j - DOUT) * DK + ko);
        }
        __builtin_amdgcn_global_load_lds(
            (const AS1 void*)bp, (AS3 void*)(smem + ((size_t)L << 3)), 16, 0, 0);
    }
    __syncthreads();

    // A row pointers (lane's output row), pre-offset by quad*8 shorts
    const short* arow[4];
    #pragma unroll
    for (int i = 0; i < 4; i++) {
        int r = row0 + wr + i * 16 + m16;
        r = r < N ? r : N - 1;
        arow[i] = A0 + (size_t)r * DK + (quad << 3);
    }
    const size_t a1d = FUSED ? (size_t)(A1 - A0) : 0;

    f32x4 acc[4][4] = {};
    const int jw = wc >> 4;

    #pragma unroll
    for (int kk = 0; kk < K32; kk++) {
        const int ko = kk * 32;
        bf16x8 af[4];
        #pragma unroll
        for (int i = 0; i < 4; i++) {
            const short* ap = arow[i];
            if (FUSED && ko >= DK) ap += a1d + (ko - DK);
            else                   ap += ko;
            af[i] = *(const bf16x8*)ap;
        }
        #pragma unroll
        for (int j = 0; j < 4; j++) {
            bf16x8 bfr = *(const bf16x8*)(smem +
                (((((jw + j) * K32 + kk) * 4 + quad) * 16 + m16) << 3));
            // swapped operands: lane's output row = m16, cols = quad*4+r
            #pragma unroll
            for (int i = 0; i < 4; i++)
                acc[i][j] = __builtin_amdgcn_mfma_f32_16x16x32_bf16(
                    bfr, af[i], acc[i][j], 0, 0, 0);
        }
    }

    __syncthreads();   // B tile dead; smem becomes epilogue scratch

    // ---- wave-private transpose epilogue: int2 LDS writes, int4 reads ----
    short* ep = smem + w * 4608;
    #pragma unroll
    for (int j = 0; j < 4; j++) {
        const int cb = wc + j * 16 + (quad << 2);
        float4 bv = make_float4(0.f, 0.f, 0.f, 0.f);
        if (FUSED) bv = *(const float4*)(bias + col0 + cb);
        #pragma unroll
        for (int i = 0; i < 4; i++) {
            float v0 = acc[i][j][0], v1 = acc[i][j][1];
            float v2 = acc[i][j][2], v3 = acc[i][j][3];
            if (FUSED) {
                v0 += bv.x; v1 += bv.y; v2 += bv.z; v3 += bv.w;
                v0 = v0 > 0.f ? v0 : 0.01f * v0;
                v1 = v1 > 0.f ? v1 : 0.01f * v1;
                v2 = v2 > 0.f ? v2 : 0.01f * v2;
                v3 = v3 > 0.f ? v3 : 0.01f * v3;
            }
            int2 pv;
            pv.x = pack2(v0, v1);
            pv.y = pack2(v2, v3);
            *(int2*)(ep + (i * 16 + m16) * 72 + j * 16 + (quad << 2)) = pv;
        }
    }
    const int r8  = lane >> 3;
    const int seg = lane & 7;
    #pragma unroll
    for (int rb = 0; rb < 8; rb++) {
        const int lrow = rb * 8 + r8;
        int4 vv = *(const int4*)(ep + lrow * 72 + seg * 8);
        const int grow = row0 + wr + lrow;
        if (grow < N)
            *(int4*)(outH + (size_t)grow * NCOLS + col0 + wc + seg * 8) = vv;
    }
}

extern "C" void kernel_launch(void* const* d_in, const int* in_sizes, int n_in,
                              void* d_out, int out_size, void* d_ws, size_t ws_size,
                              hipStream_t stream) {
    const int N = NNODES;
    const float* x  = (const float*)d_in[0];
    const int*   ei = (const int*)d_in[1];
    const int    E  = in_sizes[1] / 2;
    const int* src = ei;
    const int* dst = ei + E;

    const float* Wr[4] = { (const float*)d_in[2], (const float*)d_in[5],
                           (const float*)d_in[8], (const float*)d_in[11] };
    const float* Ws[4] = { (const float*)d_in[3], (const float*)d_in[6],
                           (const float*)d_in[9], (const float*)d_in[12] };
    const float* bb[4] = { (const float*)d_in[4], (const float*)d_in[7],
                           (const float*)d_in[10], (const float*)d_in[13] };

    float* out  = (float*)d_out;                     // h_final: N x 128 fp32
    float* emb  = out + (size_t)N * 128;             // emb:     N x 64 fp32

    // workspace layout
    short* zwbf   = (short*)d_ws;                    // N x 256 bf16 (z|w)
    short* aggbf  = zwbf + (size_t)N * 256;          // N x 128 bf16
    short* xbf    = aggbf + (size_t)N * 128;         // N x 128 bf16
    short* h1bf   = xbf + (size_t)N * 128;           // N x 256 bf16 (also h3)
    short* embbf  = h1bf + (size_t)N * 256;          // N x 64 bf16
    short* wbf    = embbf + (size_t)N * 64;          // 196608 bf16 weights
    int*   rowptr = (int*)(wbf + 196608);            // N+1
    int*   col    = rowptr + (N + 1);                // E
    int*   coarse = col + E;                         // E
    int*   histG  = coarse + E;                      // NCB*256
    int*   btot   = histG + NCB * 256;               // NCB
    int*   bases  = btot + NCB;                      // NCB+1

    const short* wr0 = wbf;           const short* ws0 = wbf + 32768;
    const short* wr1 = wbf + 65536;   const short* ws1 = wbf + 81920;
    const short* wr2 = wbf + 98304;   const short* ws2 = wbf + 114688;
    const short* wr3 = wbf + 131072;  const short* ws3 = wbf + 163840;

    const int chunk = (E + 255) / 256;
    const int gemmRB = (N + 255) / 256;              // 196 (256-row tiles)
    const int nodeBlocks = (N + 3) / 4;

    // ---- CSR build (contention-free counting sort) + converts ----
    hist_coarse<<<256, 256, 0, stream>>>(dst, histG, E, chunk);
    scan_buckets<<<NCB, 256, 0, stream>>>(histG, btot);
    scan_bases<<<1, 256, 0, stream>>>(btot, bases, E);
    scatter_coarse<<<256, 256, 0, stream>>>(src, dst, histG, bases, coarse, E, chunk);
    fill_from_coarse<<<NCB, 256, 0, stream>>>(bases, coarse, rowptr, col, N);
    cvt_x<<<(N * 128 / 4 + 255) / 256, 256, 0, stream>>>(x, xbf, N * 128 / 4);
    cvt_weights<<<(196608 + 255) / 256, 256, 0, stream>>>(
        Wr[0], Ws[0], Wr[1], Ws[1], Wr[2], Ws[2], Wr[3], Ws[3], wbf);

    // ---- Layer 0 (gather-first): 128 -> 256 ----
    gather_sum128<<<nodeBlocks, 256, 0, stream>>>(xbf, rowptr, col, aggbf, N);
    gemm_mfma<128, 256, true><<<dim3(gemmRB, 2), 512, 0, stream>>>(
        aggbf, xbf, wr0, ws0, bb[0], h1bf, N);

    // ---- Layer 1 (GEMM-first): 256 -> 64 ----
    gemm_mfma<256, 64, false><<<dim3(gemmRB, 1), 512, 0, stream>>>(
        h1bf, nullptr, wr1, ws1, nullptr, zwbf, N);            // zw1: N x 128
    gather_fin64<<<nodeBlocks, 256, 0, stream>>>(
        zwbf, rowptr, col, bb[1], emb, embbf, N);

    // ---- Layer 2 (gather-first): 64 -> 256 ----
    gather_sum64<<<nodeBlocks, 256, 0, stream>>>(embbf, rowptr, col, aggbf, N);
    gemm_mfma<64, 256, true><<<dim3(gemmRB, 2), 512, 0, stream>>>(
        aggbf, embbf, wr2, ws2, bb[2], h1bf /*h3bf*/, N);

    // ---- Layer 3 (GEMM-first): 256 -> 128 ----
    gemm_mfma<256, 128, false><<<dim3(gemmRB, 2), 512, 0, stream>>>(
        h1bf /*h3bf*/, nullptr, wr3, ws3, nullptr, zwbf, N);   // zw3: N x 256
    gather_fin128<<<nodeBlocks, 256, 0, stream>>>(
        zwbf, rowptr, col, bb[3], out, N);
}

// Round 5
// 317.266 us; speedup vs baseline: 1.1335x; 1.0213x over previous
//
#include <hip/hip_runtime.h>

#define NNODES 50000
#define NCB 196                       // coarse buckets of 256 nodes

typedef __attribute__((ext_vector_type(8))) short bf16x8;
typedef __attribute__((ext_vector_type(4))) float f32x4;

#define AS1 __attribute__((address_space(1)))
#define AS3 __attribute__((address_space(3)))

__device__ inline short f2bf(float f) {
    unsigned u = __float_as_uint(f);
    unsigned r = (u + 0x7FFFu + ((u >> 16) & 1u)) >> 16;
    return (short)r;
}
__device__ inline float bf2f(short s) {
    return __uint_as_float(((unsigned)(unsigned short)s) << 16);
}
__device__ inline float2 bfp2f(int p) {   // packed pair: low short = elem 0
    float2 f;
    f.x = __uint_as_float((unsigned)p << 16);
    f.y = __uint_as_float((unsigned)p & 0xFFFF0000u);
    return f;
}
// 8 bf16 (int4) -> 8 fp32 accumulate
__device__ inline void addbf8(float* a, int4 v) {
    float2 l0 = bfp2f(v.x), l1 = bfp2f(v.y), l2 = bfp2f(v.z), l3 = bfp2f(v.w);
    a[0] += l0.x; a[1] += l0.y; a[2] += l1.x; a[3] += l1.y;
    a[4] += l2.x; a[5] += l2.y; a[6] += l3.x; a[7] += l3.y;
}
__device__ inline int pack2(float a, float b) {
    return ((int)(unsigned short)f2bf(a)) | ((int)f2bf(b) << 16);
}

// 256-thread exclusive scan (uses lds[0..4]); includes barriers.
__device__ inline int excl_scan_256(int v, int* lds, int tid) {
    int lane = tid & 63, w = tid >> 6;
    int incl = v;
    #pragma unroll
    for (int off = 1; off < 64; off <<= 1) {
        int t = __shfl_up(incl, off, 64);
        if (lane >= off) incl += t;
    }
    if (lane == 63) lds[w] = incl;
    __syncthreads();
    if (tid == 0) {
        int s = 0;
        #pragma unroll
        for (int i = 0; i < 4; i++) { int t = lds[i]; lds[i] = s; s += t; }
    }
    __syncthreads();
    return incl - v + lds[w];
}

// ====== prep: fused hist_coarse + cvt_x + cvt_weights (independent) =========
// blocks [0,256): histogram; [256,6506): cvt_x; [6506,7274): cvt_weights
#define PREP_HIST 256
#define PREP_CVTX 6250
#define PREP_CVTW 768
__global__ __launch_bounds__(256) void prep(
    const int* __restrict__ dst, int* __restrict__ histG, int E, int chunk,
    const float* __restrict__ x, short* __restrict__ xbf,
    const float* __restrict__ p0, const float* __restrict__ p1,
    const float* __restrict__ p2, const float* __restrict__ p3,
    const float* __restrict__ p4, const float* __restrict__ p5,
    const float* __restrict__ p6, const float* __restrict__ p7,
    short* __restrict__ wbf)
{
    const int tid = threadIdx.x;
    const int bx  = blockIdx.x;
    if (bx < PREP_HIST) {
        __shared__ int h[NCB];
        for (int i = tid; i < NCB; i += 256) h[i] = 0;
        __syncthreads();
        const int beg = bx * chunk;
        const int end = min(beg + chunk, E);
        for (int e = beg + tid; e < end; e += 256)
            atomicAdd(&h[dst[e] >> 8], 1);
        __syncthreads();
        for (int i = tid; i < NCB; i += 256)
            histG[i * 256 + bx] = h[i];
    } else if (bx < PREP_HIST + PREP_CVTX) {
        const int i = (bx - PREP_HIST) * 256 + tid;
        float4 v = ((const float4*)x)[i];
        short4 s;
        s.x = f2bf(v.x); s.y = f2bf(v.y); s.z = f2bf(v.z); s.w = f2bf(v.w);
        *(short4*)(xbf + (size_t)i * 4) = s;
    } else {
        const int g = (bx - PREP_HIST - PREP_CVTX) * 256 + tid;
        const float* src; int off;
        if      (g <  32768) { src = p0; off = g; }
        else if (g <  65536) { src = p1; off = g -  32768; }
        else if (g <  81920) { src = p2; off = g -  65536; }
        else if (g <  98304) { src = p3; off = g -  81920; }
        else if (g < 114688) { src = p4; off = g -  98304; }
        else if (g < 131072) { src = p5; off = g - 114688; }
        else if (g < 163840) { src = p6; off = g - 131072; }
        else                 { src = p7; off = g - 163840; }
        wbf[g] = f2bf(src[off]);
    }
}

// ============== CSR build: contention-free counting sort ====================
__global__ __launch_bounds__(256) void scan_buckets(
    int* __restrict__ histG, int* __restrict__ btot)
{
    __shared__ int lds[8];
    const int tid = threadIdx.x;
    const int b = blockIdx.x;
    int v = histG[b * 256 + tid];
    int ex = excl_scan_256(v, lds, tid);
    histG[b * 256 + tid] = ex;
    if (tid == 255) btot[b] = ex + v;
}

__global__ __launch_bounds__(256) void scan_bases(
    const int* __restrict__ btot, int* __restrict__ bases, int E)
{
    __shared__ int lds[8];
    const int tid = threadIdx.x;
    int v = (tid < NCB) ? btot[tid] : 0;
    int ex = excl_scan_256(v, lds, tid);
    if (tid <= NCB) bases[tid] = ex;   // bases[NCB] == E
}

__global__ __launch_bounds__(256) void scatter_coarse(
    const int* __restrict__ src, const int* __restrict__ dst,
    const int* __restrict__ histG, const int* __restrict__ bases,
    int* __restrict__ coarse, int E, int chunk)
{
    __shared__ int pos[NCB];
    const int tid = threadIdx.x;
    const int blk = blockIdx.x;
    for (int i = tid; i < NCB; i += 256)
        pos[i] = bases[i] + histG[i * 256 + blk];
    __syncthreads();
    const int beg = blk * chunk;
    const int end = min(beg + chunk, E);
    for (int e = beg + tid; e < end; e += 256) {
        int d = dst[e];
        int p = atomicAdd(&pos[d >> 8], 1);
        coarse[p] = ((d & 255) << 16) | src[e];
    }
}

__global__ __launch_bounds__(256) void fill_from_coarse(
    const int* __restrict__ bases, const int* __restrict__ coarse,
    int* __restrict__ rowptr, int* __restrict__ col, int N)
{
    __shared__ int hist[256], rp[256], pos[256];
    __shared__ int lds[8];
    const int cb  = blockIdx.x;
    const int tid = threadIdx.x;
    const int n0  = cb << 8;
    const int beg = bases[cb], end = bases[cb + 1];
    hist[tid] = 0; pos[tid] = 0;
    __syncthreads();
    for (int e = beg + tid; e < end; e += 256)
        atomicAdd(&hist[coarse[e] >> 16], 1);
    __syncthreads();
    int ex = excl_scan_256(hist[tid], lds, tid);
    rp[tid] = beg + ex;
    if (n0 + tid <= N) rowptr[n0 + tid] = beg + ex;
    __syncthreads();
    for (int e = beg + tid; e < end; e += 256) {
        int pk = coarse[e];
        int dl = pk >> 16;
        int p = atomicAdd(&pos[dl], 1);
        col[rp[dl] + p] = pk & 0xFFFF;
    }
}

// ====== gather-sum, wide-window (bf16 rows, fp32 accumulate) ================
__global__ __launch_bounds__(256) void gather_sum128(
    const short* __restrict__ xbf, const int* __restrict__ rowptr,
    const int* __restrict__ col, short* __restrict__ aggbf, int N)
{
    const int wave = threadIdx.x >> 6;
    const int lane = threadIdx.x & 63;
    const int node = blockIdx.x * 4 + wave;
    if (node >= N) return;
    const int g = lane >> 4;          // edge group 0..3
    const int c = lane & 15;          // int4 slot within row (8 shorts)
    const int beg = rowptr[node], end = rowptr[node + 1];
    float acc[8] = {};
    const int last = end - 1;
    for (int e = beg; e < end; e += 16) {
        const int e0 = e + g, e1 = e + 4 + g, e2 = e + 8 + g, e3 = e + 12 + g;
        const bool m0 = e0 < end, m1 = e1 < end, m2 = e2 < end, m3 = e3 < end;
        const int i0 = col[min(e0, last)];
        const int i1 = col[min(e1, last)];
        const int i2 = col[min(e2, last)];
        const int i3 = col[min(e3, last)];
        int4 v0 = *(const int4*)(xbf + (size_t)i0 * 128 + c * 8);
        int4 v1 = *(const int4*)(xbf + (size_t)i1 * 128 + c * 8);
        int4 v2 = *(const int4*)(xbf + (size_t)i2 * 128 + c * 8);
        int4 v3 = *(const int4*)(xbf + (size_t)i3 * 128 + c * 8);
        if (m0) addbf8(acc, v0);
        if (m1) addbf8(acc, v1);
        if (m2) addbf8(acc, v2);
        if (m3) addbf8(acc, v3);
    }
    #pragma unroll
    for (int k = 0; k < 8; k++) acc[k] += __shfl_down(acc[k], 32);
    #pragma unroll
    for (int k = 0; k < 8; k++) acc[k] += __shfl_down(acc[k], 16);
    if (g == 0) {
        int4 sv;
        sv.x = pack2(acc[0], acc[1]);
        sv.y = pack2(acc[2], acc[3]);
        sv.z = pack2(acc[4], acc[5]);
        sv.w = pack2(acc[6], acc[7]);
        *(int4*)(aggbf + (size_t)node * 128 + c * 8) = sv;
    }
}

__global__ __launch_bounds__(256) void gather_sum64(
    const short* __restrict__ xbf, const int* __restrict__ rowptr,
    const int* __restrict__ col, short* __restrict__ aggbf, int N)
{
    const int wave = threadIdx.x >> 6;
    const int lane = threadIdx.x & 63;
    const int node = blockIdx.x * 4 + wave;
    if (node >= N) return;
    const int g = lane >> 3;          // edge group 0..7
    const int c = lane & 7;           // int4 slot within row
    const int beg = rowptr[node], end = rowptr[node + 1];
    float acc[8] = {};
    const int last = end - 1;
    for (int e = beg; e < end; e += 16) {
        const int e0 = e + g, e1 = e + 8 + g;
        const bool m0 = e0 < end, m1 = e1 < end;
        const int i0 = col[min(e0, last)];
        const int i1 = col[min(e1, last)];
        int4 v0 = *(const int4*)(xbf + (size_t)i0 * 64 + c * 8);
        int4 v1 = *(const int4*)(xbf + (size_t)i1 * 64 + c * 8);
        if (m0) addbf8(acc, v0);
        if (m1) addbf8(acc, v1);
    }
    #pragma unroll
    for (int k = 0; k < 8; k++) acc[k] += __shfl_down(acc[k], 32);
    #pragma unroll
    for (int k = 0; k < 8; k++) acc[k] += __shfl_down(acc[k], 16);
    #pragma unroll
    for (int k = 0; k < 8; k++) acc[k] += __shfl_down(acc[k], 8);
    if (g == 0) {
        int4 sv;
        sv.x = pack2(acc[0], acc[1]);
        sv.y = pack2(acc[2], acc[3]);
        sv.z = pack2(acc[4], acc[5]);
        sv.w = pack2(acc[6], acc[7]);
        *(int4*)(aggbf + (size_t)node * 64 + c * 8) = sv;
    }
}

// ==== gather_fin128: out128 = lrelu(seg_sum(z[src]) + w + b), zw N x 256 ====
__global__ __launch_bounds__(256) void gather_fin128(
    const short* __restrict__ zw, const int* __restrict__ rowptr,
    const int* __restrict__ col, const float* __restrict__ bias,
    float* __restrict__ out, int N)
{
    const int wave = threadIdx.x >> 6;
    const int lane = threadIdx.x & 63;
    const int node = blockIdx.x * 4 + wave;
    if (node >= N) return;
    const int g = lane >> 4;
    const int c = lane & 15;
    const int beg = rowptr[node], end = rowptr[node + 1];
    float acc[8] = {};
    if (g == 0) {   // root part + bias, added once
        int4 wv = *(const int4*)(zw + (size_t)node * 256 + 128 + c * 8);
        addbf8(acc, wv);
        float4 b0 = *(const float4*)(bias + c * 8);
        float4 b1 = *(const float4*)(bias + c * 8 + 4);
        acc[0] += b0.x; acc[1] += b0.y; acc[2] += b0.z; acc[3] += b0.w;
        acc[4] += b1.x; acc[5] += b1.y; acc[6] += b1.z; acc[7] += b1.w;
    }
    const int last = end - 1;
    for (int e = beg; e < end; e += 16) {
        const int e0 = e + g, e1 = e + 4 + g, e2 = e + 8 + g, e3 = e + 12 + g;
        const bool m0 = e0 < end, m1 = e1 < end, m2 = e2 < end, m3 = e3 < end;
        const int i0 = col[min(e0, last)];
        const int i1 = col[min(e1, last)];
        const int i2 = col[min(e2, last)];
        const int i3 = col[min(e3, last)];
        int4 v0 = *(const int4*)(zw + (size_t)i0 * 256 + c * 8);
        int4 v1 = *(const int4*)(zw + (size_t)i1 * 256 + c * 8);
        int4 v2 = *(const int4*)(zw + (size_t)i2 * 256 + c * 8);
        int4 v3 = *(const int4*)(zw + (size_t)i3 * 256 + c * 8);
        if (m0) addbf8(acc, v0);
        if (m1) addbf8(acc, v1);
        if (m2) addbf8(acc, v2);
        if (m3) addbf8(acc, v3);
    }
    #pragma unroll
    for (int k = 0; k < 8; k++) acc[k] += __shfl_down(acc[k], 32);
    #pragma unroll
    for (int k = 0; k < 8; k++) acc[k] += __shfl_down(acc[k], 16);
    if (g == 0) {
        #pragma unroll
        for (int k = 0; k < 8; k++) acc[k] = acc[k] > 0.f ? acc[k] : 0.01f * acc[k];
        float4 o0 = make_float4(acc[0], acc[1], acc[2], acc[3]);
        float4 o1 = make_float4(acc[4], acc[5], acc[6], acc[7]);
        *(float4*)(out + (size_t)node * 128 + c * 8)     = o0;
        *(float4*)(out + (size_t)node * 128 + c * 8 + 4) = o1;
    }
}

// ==== gather_fin64: emb = lrelu(seg_sum(z[src]) + w + b), zw N x 128 ========
__global__ __launch_bounds__(256) void gather_fin64(
    const short* __restrict__ zw, const int* __restrict__ rowptr,
    const int* __restrict__ col, const float* __restrict__ bias,
    float* __restrict__ out, short* __restrict__ out_bf, int N)
{
    const int wave = threadIdx.x >> 6;
    const int lane = threadIdx.x & 63;
    const int node = blockIdx.x * 4 + wave;
    if (node >= N) return;
    const int g = lane >> 3;
    const int c = lane & 7;
    const int beg = rowptr[node], end = rowptr[node + 1];
    float acc[8] = {};
    if (g == 0) {
        int4 wv = *(const int4*)(zw + (size_t)node * 128 + 64 + c * 8);
        addbf8(acc, wv);
        float4 b0 = *(const float4*)(bias + c * 8);
        float4 b1 = *(const float4*)(bias + c * 8 + 4);
        acc[0] += b0.x; acc[1] += b0.y; acc[2] += b0.z; acc[3] += b0.w;
        acc[4] += b1.x; acc[5] += b1.y; acc[6] += b1.z; acc[7] += b1.w;
    }
    const int last = end - 1;
    for (int e = beg; e < end; e += 16) {
        const int e0 = e + g, e1 = e + 8 + g;
        const bool m0 = e0 < end, m1 = e1 < end;
        const int i0 = col[min(e0, last)];
        const int i1 = col[min(e1, last)];
        int4 v0 = *(const int4*)(zw + (size_t)i0 * 128 + c * 8);
        int4 v1 = *(const int4*)(zw + (size_t)i1 * 128 + c * 8);
        if (m0) addbf8(acc, v0);
        if (m1) addbf8(acc, v1);
    }
    #pragma unroll
    for (int k = 0; k < 8; k++) acc[k] += __shfl_down(acc[k], 32);
    #pragma unroll
    for (int k = 0; k < 8; k++) acc[k] += __shfl_down(acc[k], 16);
    #pragma unroll
    for (int k = 0; k < 8; k++) acc[k] += __shfl_down(acc[k], 8);
    if (g == 0) {
        #pragma unroll
        for (int k = 0; k < 8; k++) acc[k] = acc[k] > 0.f ? acc[k] : 0.01f * acc[k];
        float4 o0 = make_float4(acc[0], acc[1], acc[2], acc[3]);
        float4 o1 = make_float4(acc[4], acc[5], acc[6], acc[7]);
        *(float4*)(out + (size_t)node * 64 + c * 8)     = o0;
        *(float4*)(out + (size_t)node * 64 + c * 8 + 4) = o1;
        int4 sv;
        sv.x = pack2(acc[0], acc[1]);
        sv.y = pack2(acc[2], acc[3]);
        sv.z = pack2(acc[4], acc[5]);
        sv.w = pack2(acc[6], acc[7]);
        *(int4*)(out_bf + (size_t)node * 64 + c * 8) = sv;
    }
}

// ======================= MFMA GEMM ==========================================
// 256-row x 128-col tile, 512 threads (8 waves: 4 row quarters x 2 col slabs).
// B tile (<=64KB) staged once via global_load_lds (linear dest, permuted
// source). K-loop: A from global, B via ds_read_b128, swapped-operand MFMA.
// Wave-private transpose epilogue (int2 LDS writes, int4 coalesced stores).
// PAIRED: flat grid with bijective swizzle so both col-halves of a row-tile
// land on the same XCD (d%8 equal) -> A-tile L2 reuse across the pair.
template<int DK, int DOUT, bool FUSED, bool PAIRED>
__global__ __launch_bounds__(512, 2) void gemm_mfma(
    const short* __restrict__ A0, const short* __restrict__ A1,
    const short* __restrict__ B0, const short* __restrict__ B1,
    const float* __restrict__ bias, short* __restrict__ outH, int N)
{
    constexpr int KTOT  = FUSED ? 2 * DK : DK;
    constexpr int NCOLS = FUSED ? DOUT : 2 * DOUT;
    constexpr int K32   = KTOT / 32;
    constexpr int LOG2K32 = (K32 == 8) ? 3 : 2;
    constexpr int BSH   = 128 * KTOT;            // B tile, shorts
    constexpr int BI4   = BSH / 8;               // int4 units
    constexpr int ITER  = BI4 / 512;
    constexpr int EPSH  = 8 * 4608;              // epilogue scratch, shorts
    constexpr int SMSH  = (BSH > EPSH) ? BSH : EPSH;
    constexpr int NPAIR = (NNODES + 255) / 256;  // 196 row tiles

    int bx, by;
    if (PAIRED) {
        const int d  = blockIdx.x;
        const int hi = d >> 4, rem = d & 15;
        const int q  = hi * 8 + (rem & 7);
        if (q >= NPAIR) return;                  // uniform per block
        bx = q; by = rem >> 3;
    } else {
        bx = blockIdx.x; by = 0;
    }

    __shared__ short smem[SMSH];
    const int tid  = threadIdx.x;
    const int row0 = bx * 256;
    const int col0 = by * 128;
    const int w    = tid >> 6;
    const int lane = tid & 63;
    const int wr   = (w & 3) << 6;               // row quarter 0/64/128/192
    const int wc   = (w >> 2) << 6;              // col slab 0/64
    const int m16  = lane & 15;
    const int quad = lane >> 4;

    // ---- stage B tile via async global->LDS: linear LDS int4-index L
    //      corresponds to [jj][kk][qd][mm]; source address permuted. ----
    #pragma unroll
    for (int it = 0; it < ITER; it++) {
        const int L  = tid + it * 512;
        const int mm = L & 15;
        const int qd = (L >> 4) & 3;
        const int kk = (L >> 6) & (K32 - 1);
        const int jj = L >> (6 + LOG2K32);
        const int j  = col0 + jj * 16 + mm;
        const int ko = (kk * 4 + qd) * 8;
        const short* bp;
        if (FUSED) {
            if (ko < DK) bp = B0 + (size_t)j * DK + ko;
            else         bp = B1 + (size_t)j * DK + (ko - DK);
        } else {
            bp = (j < DOUT) ? (B0 + (size_t)j * DK + ko)
                            : (B1 + (size_t)(j - DOUT) * DK + ko);
        }
        __builtin_amdgcn_global_load_lds(
            (const AS1 void*)bp, (AS3 void*)(smem + ((size_t)L << 3)), 16, 0, 0);
    }
    __syncthreads();

    // A row pointers (lane's output row), pre-offset by quad*8 shorts
    const short* arow[4];
    #pragma unroll
    for (int i = 0; i < 4; i++) {
        int r = row0 + wr + i * 16 + m16;
        r = r < N ? r : N - 1;
        arow[i] = A0 + (size_t)r * DK + (quad << 3);
    }
    const size_t a1d = FUSED ? (size_t)(A1 - A0) : 0;

    f32x4 acc[4][4] = {};
    const int jw = wc >> 4;

    #pragma unroll
    for (int kk = 0; kk < K32; kk++) {
        const int ko = kk * 32;
        bf16x8 af[4];
        #pragma unroll
        for (int i = 0; i < 4; i++) {
            const short* ap = arow[i];
            if (FUSED && ko >= DK) ap += a1d + (ko - DK);
            else                   ap += ko;
            af[i] = *(const bf16x8*)ap;
        }
        #pragma unroll
        for (int j = 0; j < 4; j++) {
            bf16x8 bfr = *(const bf16x8*)(smem +
                (((((jw + j) * K32 + kk) * 4 + quad) * 16 + m16) << 3));
            // swapped operands: lane's output row = m16, cols = quad*4+r
            #pragma unroll
            for (int i = 0; i < 4; i++)
                acc[i][j] = __builtin_amdgcn_mfma_f32_16x16x32_bf16(
                    bfr, af[i], acc[i][j], 0, 0, 0);
        }
    }

    __syncthreads();   // B tile dead; smem becomes epilogue scratch

    // ---- wave-private transpose epilogue: int2 LDS writes, int4 reads ----
    short* ep = smem + w * 4608;
    #pragma unroll
    for (int j = 0; j < 4; j++) {
        const int cb = wc + j * 16 + (quad << 2);
        float4 bv = make_float4(0.f, 0.f, 0.f, 0.f);
        if (FUSED) bv = *(const float4*)(bias + col0 + cb);
        #pragma unroll
        for (int i = 0; i < 4; i++) {
            float v0 = acc[i][j][0], v1 = acc[i][j][1];
            float v2 = acc[i][j][2], v3 = acc[i][j][3];
            if (FUSED) {
                v0 += bv.x; v1 += bv.y; v2 += bv.z; v3 += bv.w;
                v0 = v0 > 0.f ? v0 : 0.01f * v0;
                v1 = v1 > 0.f ? v1 : 0.01f * v1;
                v2 = v2 > 0.f ? v2 : 0.01f * v2;
                v3 = v3 > 0.f ? v3 : 0.01f * v3;
            }
            int2 pv;
            pv.x = pack2(v0, v1);
            pv.y = pack2(v2, v3);
            *(int2*)(ep + (i * 16 + m16) * 72 + j * 16 + (quad << 2)) = pv;
        }
    }
    const int r8  = lane >> 3;
    const int seg = lane & 7;
    #pragma unroll
    for (int rb = 0; rb < 8; rb++) {
        const int lrow = rb * 8 + r8;
        int4 vv = *(const int4*)(ep + lrow * 72 + seg * 8);
        const int grow = row0 + wr + lrow;
        if (grow < N)
            *(int4*)(outH + (size_t)grow * NCOLS + col0 + wc + seg * 8) = vv;
    }
}

extern "C" void kernel_launch(void* const* d_in, const int* in_sizes, int n_in,
                              void* d_out, int out_size, void* d_ws, size_t ws_size,
                              hipStream_t stream) {
    const int N = NNODES;
    const float* x  = (const float*)d_in[0];
    const int*   ei = (const int*)d_in[1];
    const int    E  = in_sizes[1] / 2;
    const int* src = ei;
    const int* dst = ei + E;

    const float* Wr[4] = { (const float*)d_in[2], (const float*)d_in[5],
                           (const float*)d_in[8], (const float*)d_in[11] };
    const float* Ws[4] = { (const float*)d_in[3], (const float*)d_in[6],
                           (const float*)d_in[9], (const float*)d_in[12] };
    const float* bb[4] = { (const float*)d_in[4], (const float*)d_in[7],
                           (const float*)d_in[10], (const float*)d_in[13] };

    float* out  = (float*)d_out;                     // h_final: N x 128 fp32
    float* emb  = out + (size_t)N * 128;             // emb:     N x 64 fp32

    // workspace layout
    short* zwbf   = (short*)d_ws;                    // N x 256 bf16 (z|w)
    short* aggbf  = zwbf + (size_t)N * 256;          // N x 128 bf16
    short* xbf    = aggbf + (size_t)N * 128;         // N x 128 bf16
    short* h1bf   = xbf + (size_t)N * 128;           // N x 256 bf16 (also h3)
    short* embbf  = h1bf + (size_t)N * 256;          // N x 64 bf16
    short* wbf    = embbf + (size_t)N * 64;          // 196608 bf16 weights
    int*   rowptr = (int*)(wbf + 196608);            // N+1
    int*   col    = rowptr + (N + 1);                // E
    int*   coarse = col + E;                         // E
    int*   histG  = coarse + E;                      // NCB*256
    int*   btot   = histG + NCB * 256;               // NCB
    int*   bases  = btot + NCB;                      // NCB+1

    const short* wr0 = wbf;           const short* ws0 = wbf + 32768;
    const short* wr1 = wbf + 65536;   const short* ws1 = wbf + 81920;
    const short* wr2 = wbf + 98304;   const short* ws2 = wbf + 114688;
    const short* wr3 = wbf + 131072;  const short* ws3 = wbf + 163840;

    const int chunk = (E + 255) / 256;
    const int gemmRB = (N + 255) / 256;              // 196 (256-row tiles)
    const int pairGrid = ((gemmRB + 7) / 8) * 16;    // 400 (8 dead blocks)
    const int nodeBlocks = (N + 3) / 4;

    // ---- CSR build + converts (prep fuses hist + cvt_x + cvt_weights) ----
    prep<<<PREP_HIST + PREP_CVTX + PREP_CVTW, 256, 0, stream>>>(
        dst, histG, E, chunk, x, xbf,
        Wr[0], Ws[0], Wr[1], Ws[1], Wr[2], Ws[2], Wr[3], Ws[3], wbf);
    scan_buckets<<<NCB, 256, 0, stream>>>(histG, btot);
    scan_bases<<<1, 256, 0, stream>>>(btot, bases, E);
    scatter_coarse<<<256, 256, 0, stream>>>(src, dst, histG, bases, coarse, E, chunk);
    fill_from_coarse<<<NCB, 256, 0, stream>>>(bases, coarse, rowptr, col, N);

    // ---- Layer 0 (gather-first): 128 -> 256 ----
    gather_sum128<<<nodeBlocks, 256, 0, stream>>>(xbf, rowptr, col, aggbf, N);
    gemm_mfma<128, 256, true, true><<<pairGrid, 512, 0, stream>>>(
        aggbf, xbf, wr0, ws0, bb[0], h1bf, N);

    // ---- Layer 1 (GEMM-first): 256 -> 64 ----
    gemm_mfma<256, 64, false, false><<<gemmRB, 512, 0, stream>>>(
        h1bf, nullptr, wr1, ws1, nullptr, zwbf, N);            // zw1: N x 128
    gather_fin64<<<nodeBlocks, 256, 0, stream>>>(
        zwbf, rowptr, col, bb[1], emb, embbf, N);

    // ---- Layer 2 (gather-first): 64 -> 256 ----
    gather_sum64<<<nodeBlocks, 256, 0, stream>>>(embbf, rowptr, col, aggbf, N);
    gemm_mfma<64, 256, true, true><<<pairGrid, 512, 0, stream>>>(
        aggbf, embbf, wr2, ws2, bb[2], h1bf /*h3bf*/, N);

    // ---- Layer 3 (GEMM-first): 256 -> 128 ----
    gemm_mfma<256, 128, false, true><<<pairGrid, 512, 0, stream>>>(
        h1bf /*h3bf*/, nullptr, wr3, ws3, nullptr, zwbf, N);   // zw3: N x 256
    gather_fin128<<<nodeBlocks, 256, 0, stream>>>(
        zwbf, rowptr, col, bb[3], out, N);
}

// Round 6
// 308.506 us; speedup vs baseline: 1.1657x; 1.0284x over previous
//
#include <hip/hip_runtime.h>

#define NNODES 50000
#define NCB 196                       // coarse buckets of 256 nodes

typedef __attribute__((ext_vector_type(8))) short bf16x8;
typedef __attribute__((ext_vector_type(4))) float f32x4;

#define AS1 __attribute__((address_space(1)))
#define AS3 __attribute__((address_space(3)))

__device__ inline short f2bf(float f) {
    unsigned u = __float_as_uint(f);
    unsigned r = (u + 0x7FFFu + ((u >> 16) & 1u)) >> 16;
    return (short)r;
}
__device__ inline float bf2f(short s) {
    return __uint_as_float(((unsigned)(unsigned short)s) << 16);
}
__device__ inline float2 bfp2f(int p) {   // packed pair: low short = elem 0
    float2 f;
    f.x = __uint_as_float((unsigned)p << 16);
    f.y = __uint_as_float((unsigned)p & 0xFFFF0000u);
    return f;
}
// 8 bf16 (int4) -> 8 fp32 accumulate
__device__ inline void addbf8(float* a, int4 v) {
    float2 l0 = bfp2f(v.x), l1 = bfp2f(v.y), l2 = bfp2f(v.z), l3 = bfp2f(v.w);
    a[0] += l0.x; a[1] += l0.y; a[2] += l1.x; a[3] += l1.y;
    a[4] += l2.x; a[5] += l2.y; a[6] += l3.x; a[7] += l3.y;
}
__device__ inline int pack2(float a, float b) {
    return ((int)(unsigned short)f2bf(a)) | ((int)f2bf(b) << 16);
}

// 256-thread exclusive scan (uses lds[0..4]); includes barriers.
__device__ inline int excl_scan_256(int v, int* lds, int tid) {
    int lane = tid & 63, w = tid >> 6;
    int incl = v;
    #pragma unroll
    for (int off = 1; off < 64; off <<= 1) {
        int t = __shfl_up(incl, off, 64);
        if (lane >= off) incl += t;
    }
    if (lane == 63) lds[w] = incl;
    __syncthreads();
    if (tid == 0) {
        int s = 0;
        #pragma unroll
        for (int i = 0; i < 4; i++) { int t = lds[i]; lds[i] = s; s += t; }
    }
    __syncthreads();
    return incl - v + lds[w];
}

// ====== prep: fused hist_coarse + cvt_x + cvt_weights (independent) =========
// blocks [0,256): histogram; [256,6506): cvt_x; [6506,7274): cvt_weights
#define PREP_HIST 256
#define PREP_CVTX 6250
#define PREP_CVTW 768
__global__ __launch_bounds__(256) void prep(
    const int* __restrict__ dst, int* __restrict__ histG, int E, int chunk,
    const float* __restrict__ x, short* __restrict__ xbf,
    const float* __restrict__ p0, const float* __restrict__ p1,
    const float* __restrict__ p2, const float* __restrict__ p3,
    const float* __restrict__ p4, const float* __restrict__ p5,
    const float* __restrict__ p6, const float* __restrict__ p7,
    short* __restrict__ wbf)
{
    const int tid = threadIdx.x;
    const int bx  = blockIdx.x;
    if (bx < PREP_HIST) {
        __shared__ int h[NCB];
        for (int i = tid; i < NCB; i += 256) h[i] = 0;
        __syncthreads();
        const int beg = bx * chunk;
        const int end = min(beg + chunk, E);
        for (int e = beg + tid; e < end; e += 256)
            atomicAdd(&h[dst[e] >> 8], 1);
        __syncthreads();
        for (int i = tid; i < NCB; i += 256)
            histG[i * 256 + bx] = h[i];
    } else if (bx < PREP_HIST + PREP_CVTX) {
        const int i = (bx - PREP_HIST) * 256 + tid;
        float4 v = ((const float4*)x)[i];
        short4 s;
        s.x = f2bf(v.x); s.y = f2bf(v.y); s.z = f2bf(v.z); s.w = f2bf(v.w);
        *(short4*)(xbf + (size_t)i * 4) = s;
    } else {
        const int g = (bx - PREP_HIST - PREP_CVTX) * 256 + tid;
        const float* src; int off;
        if      (g <  32768) { src = p0; off = g; }
        else if (g <  65536) { src = p1; off = g -  32768; }
        else if (g <  81920) { src = p2; off = g -  65536; }
        else if (g <  98304) { src = p3; off = g -  81920; }
        else if (g < 114688) { src = p4; off = g -  98304; }
        else if (g < 131072) { src = p5; off = g - 114688; }
        else if (g < 163840) { src = p6; off = g - 131072; }
        else                 { src = p7; off = g - 163840; }
        wbf[g] = f2bf(src[off]);
    }
}

// ============== CSR build: contention-free counting sort ====================
__global__ __launch_bounds__(256) void scan_buckets(
    int* __restrict__ histG, int* __restrict__ btot)
{
    __shared__ int lds[8];
    const int tid = threadIdx.x;
    const int b = blockIdx.x;
    int v = histG[b * 256 + tid];
    int ex = excl_scan_256(v, lds, tid);
    histG[b * 256 + tid] = ex;
    if (tid == 255) btot[b] = ex + v;
}

__global__ __launch_bounds__(256) void scan_bases(
    const int* __restrict__ btot, int* __restrict__ bases, int E)
{
    __shared__ int lds[8];
    const int tid = threadIdx.x;
    int v = (tid < NCB) ? btot[tid] : 0;
    int ex = excl_scan_256(v, lds, tid);
    if (tid <= NCB) bases[tid] = ex;   // bases[NCB] == E
}

__global__ __launch_bounds__(256) void scatter_coarse(
    const int* __restrict__ src, const int* __restrict__ dst,
    const int* __restrict__ histG, const int* __restrict__ bases,
    int* __restrict__ coarse, int E, int chunk)
{
    __shared__ int pos[NCB];
    const int tid = threadIdx.x;
    const int blk = blockIdx.x;
    for (int i = tid; i < NCB; i += 256)
        pos[i] = bases[i] + histG[i * 256 + blk];
    __syncthreads();
    const int beg = blk * chunk;
    const int end = min(beg + chunk, E);
    for (int e = beg + tid; e < end; e += 256) {
        int d = dst[e];
        int p = atomicAdd(&pos[d >> 8], 1);
        coarse[p] = ((d & 255) << 16) | src[e];
    }
}

__global__ __launch_bounds__(256) void fill_from_coarse(
    const int* __restrict__ bases, const int* __restrict__ coarse,
    int* __restrict__ rowptr, int* __restrict__ col, int N)
{
    __shared__ int hist[256], rp[256], pos[256];
    __shared__ int lds[8];
    const int cb  = blockIdx.x;
    const int tid = threadIdx.x;
    const int n0  = cb << 8;
    const int beg = bases[cb], end = bases[cb + 1];
    hist[tid] = 0; pos[tid] = 0;
    __syncthreads();
    for (int e = beg + tid; e < end; e += 256)
        atomicAdd(&hist[coarse[e] >> 16], 1);
    __syncthreads();
    int ex = excl_scan_256(hist[tid], lds, tid);
    rp[tid] = beg + ex;
    if (n0 + tid <= N) rowptr[n0 + tid] = beg + ex;
    __syncthreads();
    for (int e = beg + tid; e < end; e += 256) {
        int pk = coarse[e];
        int dl = pk >> 16;
        int p = atomicAdd(&pos[dl], 1);
        col[rp[dl] + p] = pk & 0xFFFF;
    }
}

// ====== gather-sum, 32-edge windows, batched index loads ====================
// D=128 (256B rows): 4 groups x 16 lanes, 8 row-loads/lane in flight.
__global__ __launch_bounds__(256) void gather_sum128(
    const short* __restrict__ xbf, const int* __restrict__ rowptr,
    const int* __restrict__ col, short* __restrict__ aggbf, int N)
{
    const int wave = threadIdx.x >> 6;
    const int lane = threadIdx.x & 63;
    const int node = blockIdx.x * 4 + wave;
    if (node >= N) return;
    const int g = lane >> 4;          // edge group 0..3
    const int c = lane & 15;          // int4 slot within row (8 shorts)
    const int beg = rowptr[node], end = rowptr[node + 1];
    float acc[8] = {};
    const int last = end - 1;
    for (int e = beg; e < end; e += 32) {
        int idx[8];
        #pragma unroll
        for (int t = 0; t < 8; t++)
            idx[t] = col[min(e + t * 4 + g, last)];
        int4 v[8];
        #pragma unroll
        for (int t = 0; t < 8; t++)
            v[t] = *(const int4*)(xbf + (size_t)idx[t] * 128 + c * 8);
        #pragma unroll
        for (int t = 0; t < 8; t++)
            if (e + t * 4 + g < end) addbf8(acc, v[t]);
    }
    #pragma unroll
    for (int k = 0; k < 8; k++) acc[k] += __shfl_down(acc[k], 32);
    #pragma unroll
    for (int k = 0; k < 8; k++) acc[k] += __shfl_down(acc[k], 16);
    if (g == 0) {
        int4 sv;
        sv.x = pack2(acc[0], acc[1]);
        sv.y = pack2(acc[2], acc[3]);
        sv.z = pack2(acc[4], acc[5]);
        sv.w = pack2(acc[6], acc[7]);
        *(int4*)(aggbf + (size_t)node * 128 + c * 8) = sv;
    }
}

// D=64 (128B rows): 8 groups x 8 lanes, 4 row-loads/lane in flight.
__global__ __launch_bounds__(256) void gather_sum64(
    const short* __restrict__ xbf, const int* __restrict__ rowptr,
    const int* __restrict__ col, short* __restrict__ aggbf, int N)
{
    const int wave = threadIdx.x >> 6;
    const int lane = threadIdx.x & 63;
    const int node = blockIdx.x * 4 + wave;
    if (node >= N) return;
    const int g = lane >> 3;          // edge group 0..7
    const int c = lane & 7;           // int4 slot within row
    const int beg = rowptr[node], end = rowptr[node + 1];
    float acc[8] = {};
    const int last = end - 1;
    for (int e = beg; e < end; e += 32) {
        int idx[4];
        #pragma unroll
        for (int t = 0; t < 4; t++)
            idx[t] = col[min(e + t * 8 + g, last)];
        int4 v[4];
        #pragma unroll
        for (int t = 0; t < 4; t++)
            v[t] = *(const int4*)(xbf + (size_t)idx[t] * 64 + c * 8);
        #pragma unroll
        for (int t = 0; t < 4; t++)
            if (e + t * 8 + g < end) addbf8(acc, v[t]);
    }
    #pragma unroll
    for (int k = 0; k < 8; k++) acc[k] += __shfl_down(acc[k], 32);
    #pragma unroll
    for (int k = 0; k < 8; k++) acc[k] += __shfl_down(acc[k], 16);
    #pragma unroll
    for (int k = 0; k < 8; k++) acc[k] += __shfl_down(acc[k], 8);
    if (g == 0) {
        int4 sv;
        sv.x = pack2(acc[0], acc[1]);
        sv.y = pack2(acc[2], acc[3]);
        sv.z = pack2(acc[4], acc[5]);
        sv.w = pack2(acc[6], acc[7]);
        *(int4*)(aggbf + (size_t)node * 64 + c * 8) = sv;
    }
}

// ==== gather_fin128: out128 = lrelu(seg_sum(z[src]) + w + b), zw N x 256 ====
__global__ __launch_bounds__(256) void gather_fin128(
    const short* __restrict__ zw, const int* __restrict__ rowptr,
    const int* __restrict__ col, const float* __restrict__ bias,
    float* __restrict__ out, int N)
{
    const int wave = threadIdx.x >> 6;
    const int lane = threadIdx.x & 63;
    const int node = blockIdx.x * 4 + wave;
    if (node >= N) return;
    const int g = lane >> 4;
    const int c = lane & 15;
    const int beg = rowptr[node], end = rowptr[node + 1];
    float acc[8] = {};
    if (g == 0) {   // root part + bias, added once
        int4 wv = *(const int4*)(zw + (size_t)node * 256 + 128 + c * 8);
        addbf8(acc, wv);
        float4 b0 = *(const float4*)(bias + c * 8);
        float4 b1 = *(const float4*)(bias + c * 8 + 4);
        acc[0] += b0.x; acc[1] += b0.y; acc[2] += b0.z; acc[3] += b0.w;
        acc[4] += b1.x; acc[5] += b1.y; acc[6] += b1.z; acc[7] += b1.w;
    }
    const int last = end - 1;
    for (int e = beg; e < end; e += 32) {
        int idx[8];
        #pragma unroll
        for (int t = 0; t < 8; t++)
            idx[t] = col[min(e + t * 4 + g, last)];
        int4 v[8];
        #pragma unroll
        for (int t = 0; t < 8; t++)
            v[t] = *(const int4*)(zw + (size_t)idx[t] * 256 + c * 8);
        #pragma unroll
        for (int t = 0; t < 8; t++)
            if (e + t * 4 + g < end) addbf8(acc, v[t]);
    }
    #pragma unroll
    for (int k = 0; k < 8; k++) acc[k] += __shfl_down(acc[k], 32);
    #pragma unroll
    for (int k = 0; k < 8; k++) acc[k] += __shfl_down(acc[k], 16);
    if (g == 0) {
        #pragma unroll
        for (int k = 0; k < 8; k++) acc[k] = acc[k] > 0.f ? acc[k] : 0.01f * acc[k];
        float4 o0 = make_float4(acc[0], acc[1], acc[2], acc[3]);
        float4 o1 = make_float4(acc[4], acc[5], acc[6], acc[7]);
        *(float4*)(out + (size_t)node * 128 + c * 8)     = o0;
        *(float4*)(out + (size_t)node * 128 + c * 8 + 4) = o1;
    }
}

// ==== gather_fin64: emb = lrelu(seg_sum(z[src]) + w + b), zw N x 128 ========
__global__ __launch_bounds__(256) void gather_fin64(
    const short* __restrict__ zw, const int* __restrict__ rowptr,
    const int* __restrict__ col, const float* __restrict__ bias,
    float* __restrict__ out, short* __restrict__ out_bf, int N)
{
    const int wave = threadIdx.x >> 6;
    const int lane = threadIdx.x & 63;
    const int node = blockIdx.x * 4 + wave;
    if (node >= N) return;
    const int g = lane >> 3;
    const int c = lane & 7;
    const int beg = rowptr[node], end = rowptr[node + 1];
    float acc[8] = {};
    if (g == 0) {
        int4 wv = *(const int4*)(zw + (size_t)node * 128 + 64 + c * 8);
        addbf8(acc, wv);
        float4 b0 = *(const float4*)(bias + c * 8);
        float4 b1 = *(const float4*)(bias + c * 8 + 4);
        acc[0] += b0.x; acc[1] += b0.y; acc[2] += b0.z; acc[3] += b0.w;
        acc[4] += b1.x; acc[5] += b1.y; acc[6] += b1.z; acc[7] += b1.w;
    }
    const int last = end - 1;
    for (int e = beg; e < end; e += 32) {
        int idx[4];
        #pragma unroll
        for (int t = 0; t < 4; t++)
            idx[t] = col[min(e + t * 8 + g, last)];
        int4 v[4];
        #pragma unroll
        for (int t = 0; t < 4; t++)
            v[t] = *(const int4*)(zw + (size_t)idx[t] * 128 + c * 8);
        #pragma unroll
        for (int t = 0; t < 4; t++)
            if (e + t * 8 + g < end) addbf8(acc, v[t]);
    }
    #pragma unroll
    for (int k = 0; k < 8; k++) acc[k] += __shfl_down(acc[k], 32);
    #pragma unroll
    for (int k = 0; k < 8; k++) acc[k] += __shfl_down(acc[k], 16);
    #pragma unroll
    for (int k = 0; k < 8; k++) acc[k] += __shfl_down(acc[k], 8);
    if (g == 0) {
        #pragma unroll
        for (int k = 0; k < 8; k++) acc[k] = acc[k] > 0.f ? acc[k] : 0.01f * acc[k];
        float4 o0 = make_float4(acc[0], acc[1], acc[2], acc[3]);
        float4 o1 = make_float4(acc[4], acc[5], acc[6], acc[7]);
        *(float4*)(out + (size_t)node * 64 + c * 8)     = o0;
        *(float4*)(out + (size_t)node * 64 + c * 8 + 4) = o1;
        int4 sv;
        sv.x = pack2(acc[0], acc[1]);
        sv.y = pack2(acc[2], acc[3]);
        sv.z = pack2(acc[4], acc[5]);
        sv.w = pack2(acc[6], acc[7]);
        *(int4*)(out_bf + (size_t)node * 64 + c * 8) = sv;
    }
}

// ======================= MFMA GEMM ==========================================
// 256-row x 128-col tile, 512 threads (8 waves: 4 row quarters x 2 col slabs).
// B tile (<=64KB) staged once via global_load_lds (linear dest, permuted
// source). K-loop: A from global, B via ds_read_b128, swapped-operand MFMA.
// Wave-private transpose epilogue (int2 LDS writes, int4 coalesced stores).
// PAIRED: flat grid with bijective swizzle so both col-halves of a row-tile
// land on the same XCD (d%8 equal) -> A-tile L2 reuse across the pair.
template<int DK, int DOUT, bool FUSED, bool PAIRED>
__global__ __launch_bounds__(512, 2) void gemm_mfma(
    const short* __restrict__ A0, const short* __restrict__ A1,
    const short* __restrict__ B0, const short* __restrict__ B1,
    const float* __restrict__ bias, short* __restrict__ outH, int N)
{
    constexpr int KTOT  = FUSED ? 2 * DK : DK;
    constexpr int NCOLS = FUSED ? DOUT : 2 * DOUT;
    constexpr int K32   = KTOT / 32;
    constexpr int LOG2K32 = (K32 == 8) ? 3 : 2;
    constexpr int BSH   = 128 * KTOT;            // B tile, shorts
    constexpr int BI4   = BSH / 8;               // int4 units
    constexpr int ITER  = BI4 / 512;
    constexpr int EPSH  = 8 * 4608;              // epilogue scratch, shorts
    constexpr int SMSH  = (BSH > EPSH) ? BSH : EPSH;
    constexpr int NPAIR = (NNODES + 255) / 256;  // 196 row tiles

    int bx, by;
    if (PAIRED) {
        const int d  = blockIdx.x;
        const int hi = d >> 4, rem = d & 15;
        const int q  = hi * 8 + (rem & 7);
        if (q >= NPAIR) return;                  // uniform per block
        bx = q; by = rem >> 3;
    } else {
        bx = blockIdx.x; by = 0;
    }

    __shared__ short smem[SMSH];
    const int tid  = threadIdx.x;
    const int row0 = bx * 256;
    const int col0 = by * 128;
    const int w    = tid >> 6;
    const int lane = tid & 63;
    const int wr   = (w & 3) << 6;               // row quarter 0/64/128/192
    const int wc   = (w >> 2) << 6;              // col slab 0/64
    const int m16  = lane & 15;
    const int quad = lane >> 4;

    // ---- stage B tile via async global->LDS: linear LDS int4-index L
    //      corresponds to [jj][kk][qd][mm]; source address permuted. ----
    #pragma unroll
    for (int it = 0; it < ITER; it++) {
        const int L  = tid + it * 512;
        const int mm = L & 15;
        const int qd = (L >> 4) & 3;
        const int kk = (L >> 6) & (K32 - 1);
        const int jj = L >> (6 + LOG2K32);
        const int j  = col0 + jj * 16 + mm;
        const int ko = (kk * 4 + qd) * 8;
        const short* bp;
        if (FUSED) {
            if (ko < DK) bp = B0 + (size_t)j * DK + ko;
            else         bp = B1 + (size_t)j * DK + (ko - DK);
        } else {
            bp = (j < DOUT) ? (B0 + (size_t)j * DK + ko)
                            : (B1 + (size_t)(j - DOUT) * DK + ko);
        }
        __builtin_amdgcn_global_load_lds(
            (const AS1 void*)bp, (AS3 void*)(smem + ((size_t)L << 3)), 16, 0, 0);
    }
    __syncthreads();

    // A row pointers (lane's output row), pre-offset by quad*8 shorts
    const short* arow[4];
    #pragma unroll
    for (int i = 0; i < 4; i++) {
        int r = row0 + wr + i * 16 + m16;
        r = r < N ? r : N - 1;
        arow[i] = A0 + (size_t)r * DK + (quad << 3);
    }
    const size_t a1d = FUSED ? (size_t)(A1 - A0) : 0;

    f32x4 acc[4][4] = {};
    const int jw = wc >> 4;

    #pragma unroll
    for (int kk = 0; kk < K32; kk++) {
        const int ko = kk * 32;
        bf16x8 af[4];
        #pragma unroll
        for (int i = 0; i < 4; i++) {
            const short* ap = arow[i];
            if (FUSED && ko >= DK) ap += a1d + (ko - DK);
            else                   ap += ko;
            af[i] = *(const bf16x8*)ap;
        }
        #pragma unroll
        for (int j = 0; j < 4; j++) {
            bf16x8 bfr = *(const bf16x8*)(smem +
                (((((jw + j) * K32 + kk) * 4 + quad) * 16 + m16) << 3));
            // swapped operands: lane's output row = m16, cols = quad*4+r
            #pragma unroll
            for (int i = 0; i < 4; i++)
                acc[i][j] = __builtin_amdgcn_mfma_f32_16x16x32_bf16(
                    bfr, af[i], acc[i][j], 0, 0, 0);
        }
    }

    __syncthreads();   // B tile dead; smem becomes epilogue scratch

    // ---- wave-private transpose epilogue: int2 LDS writes, int4 reads ----
    short* ep = smem + w * 4608;
    #pragma unroll
    for (int j = 0; j < 4; j++) {
        const int cb = wc + j * 16 + (quad << 2);
        float4 bv = make_float4(0.f, 0.f, 0.f, 0.f);
        if (FUSED) bv = *(const float4*)(bias + col0 + cb);
        #pragma unroll
        for (int i = 0; i < 4; i++) {
            float v0 = acc[i][j][0], v1 = acc[i][j][1];
            float v2 = acc[i][j][2], v3 = acc[i][j][3];
            if (FUSED) {
                v0 += bv.x; v1 += bv.y; v2 += bv.z; v3 += bv.w;
                v0 = v0 > 0.f ? v0 : 0.01f * v0;
                v1 = v1 > 0.f ? v1 : 0.01f * v1;
                v2 = v2 > 0.f ? v2 : 0.01f * v2;
                v3 = v3 > 0.f ? v3 : 0.01f * v3;
            }
            int2 pv;
            pv.x = pack2(v0, v1);
            pv.y = pack2(v2, v3);
            *(int2*)(ep + (i * 16 + m16) * 72 + j * 16 + (quad << 2)) = pv;
        }
    }
    const int r8  = lane >> 3;
    const int seg = lane & 7;
    #pragma unroll
    for (int rb = 0; rb < 8; rb++) {
        const int lrow = rb * 8 + r8;
        int4 vv = *(const int4*)(ep + lrow * 72 + seg * 8);
        const int grow = row0 + wr + lrow;
        if (grow < N)
            *(int4*)(outH + (size_t)grow * NCOLS + col0 + wc + seg * 8) = vv;
    }
}

extern "C" void kernel_launch(void* const* d_in, const int* in_sizes, int n_in,
                              void* d_out, int out_size, void* d_ws, size_t ws_size,
                              hipStream_t stream) {
    const int N = NNODES;
    const float* x  = (const float*)d_in[0];
    const int*   ei = (const int*)d_in[1];
    const int    E  = in_sizes[1] / 2;
    const int* src = ei;
    const int* dst = ei + E;

    const float* Wr[4] = { (const float*)d_in[2], (const float*)d_in[5],
                           (const float*)d_in[8], (const float*)d_in[11] };
    const float* Ws[4] = { (const float*)d_in[3], (const float*)d_in[6],
                           (const float*)d_in[9], (const float*)d_in[12] };
    const float* bb[4] = { (const float*)d_in[4], (const float*)d_in[7],
                           (const float*)d_in[10], (const float*)d_in[13] };

    float* out  = (float*)d_out;                     // h_final: N x 128 fp32
    float* emb  = out + (size_t)N * 128;             // emb:     N x 64 fp32

    // workspace layout
    short* zwbf   = (short*)d_ws;                    // N x 256 bf16 (z|w)
    short* aggbf  = zwbf + (size_t)N * 256;          // N x 128 bf16
    short* xbf    = aggbf + (size_t)N * 128;         // N x 128 bf16
    short* h1bf   = xbf + (size_t)N * 128;           // N x 256 bf16 (also h3)
    short* embbf  = h1bf + (size_t)N * 256;          // N x 64 bf16
    short* wbf    = embbf + (size_t)N * 64;          // 196608 bf16 weights
    int*   rowptr = (int*)(wbf + 196608);            // N+1
    int*   col    = rowptr + (N + 1);                // E
    int*   coarse = col + E;                         // E
    int*   histG  = coarse + E;                      // NCB*256
    int*   btot   = histG + NCB * 256;               // NCB
    int*   bases  = btot + NCB;                      // NCB+1

    const short* wr0 = wbf;           const short* ws0 = wbf + 32768;
    const short* wr1 = wbf + 65536;   const short* ws1 = wbf + 81920;
    const short* wr2 = wbf + 98304;   const short* ws2 = wbf + 114688;
    const short* wr3 = wbf + 131072;  const short* ws3 = wbf + 163840;

    const int chunk = (E + 255) / 256;
    const int gemmRB = (N + 255) / 256;              // 196 (256-row tiles)
    const int pairGrid = ((gemmRB + 7) / 8) * 16;    // 400 (8 dead blocks)
    const int nodeBlocks = (N + 3) / 4;

    // ---- CSR build + converts (prep fuses hist + cvt_x + cvt_weights) ----
    prep<<<PREP_HIST + PREP_CVTX + PREP_CVTW, 256, 0, stream>>>(
        dst, histG, E, chunk, x, xbf,
        Wr[0], Ws[0], Wr[1], Ws[1], Wr[2], Ws[2], Wr[3], Ws[3], wbf);
    scan_buckets<<<NCB, 256, 0, stream>>>(histG, btot);
    scan_bases<<<1, 256, 0, stream>>>(btot, bases, E);
    scatter_coarse<<<256, 256, 0, stream>>>(src, dst, histG, bases, coarse, E, chunk);
    fill_from_coarse<<<NCB, 256, 0, stream>>>(bases, coarse, rowptr, col, N);

    // ---- Layer 0 (gather-first): 128 -> 256 ----
    gather_sum128<<<nodeBlocks, 256, 0, stream>>>(xbf, rowptr, col, aggbf, N);
    gemm_mfma<128, 256, true, true><<<pairGrid, 512, 0, stream>>>(
        aggbf, xbf, wr0, ws0, bb[0], h1bf, N);

    // ---- Layer 1 (GEMM-first): 256 -> 64 ----
    gemm_mfma<256, 64, false, false><<<gemmRB, 512, 0, stream>>>(
        h1bf, nullptr, wr1, ws1, nullptr, zwbf, N);            // zw1: N x 128
    gather_fin64<<<nodeBlocks, 256, 0, stream>>>(
        zwbf, rowptr, col, bb[1], emb, embbf, N);

    // ---- Layer 2 (gather-first): 64 -> 256 ----
    gather_sum64<<<nodeBlocks, 256, 0, stream>>>(embbf, rowptr, col, aggbf, N);
    gemm_mfma<64, 256, true, true><<<pairGrid, 512, 0, stream>>>(
        aggbf, embbf, wr2, ws2, bb[2], h1bf /*h3bf*/, N);

    // ---- Layer 3 (GEMM-first): 256 -> 128 ----
    gemm_mfma<256, 128, false, true><<<pairGrid, 512, 0, stream>>>(
        h1bf /*h3bf*/, nullptr, wr3, ws3, nullptr, zwbf, N);   // zw3: N x 256
    gather_fin128<<<nodeBlocks, 256, 0, stream>>>(
        zwbf, rowptr, col, bb[3], out, N);
}